// Round 1
// baseline (19191.811 us; speedup 1.0000x reference)
//
#include <hip/hip_runtime.h>
#include <cstdint>

#define WG 256
#define CI 8

// ---------------------------------------------------------------------------
// adjacency kernel: h[n][c][w][t] = sum_v A[v][w] * f[n][c][v][t]   (no relu)
// FROM_X: f is the raw input x in [n][300][25][3] layout (c < 3).
// ---------------------------------------------------------------------------
template<bool FROM_X>
__global__ __launch_bounds__(WG)
void adj_kernel(const float* __restrict__ f, const float* __restrict__ Am,
                float* __restrict__ h, int C, int T)
{
    __shared__ __align__(16) float A_s[25][28];
    const int tid = threadIdx.x;
    for (int i2 = tid; i2 < 625; i2 += WG) A_s[i2 / 25][i2 % 25] = Am[i2];
    __syncthreads();

    const int n = blockIdx.y;
    const int idx = blockIdx.x * WG + tid;
    if (idx >= C * T) return;
    const int c = idx / T;
    const int t = idx - c * T;

    float acc[25];
#pragma unroll
    for (int w = 0; w < 25; ++w) acc[w] = 0.f;

    for (int v = 0; v < 25; ++v) {
        float fv;
        if (FROM_X) fv = f[((size_t)n * T + t) * 75 + v * 3 + c];
        else        fv = f[(((size_t)n * C + c) * 25 + v) * T + t];
#pragma unroll
        for (int j = 0; j < 6; ++j) {
            float4 a4 = *(const float4*)&A_s[v][j * 4];
            acc[j * 4 + 0] = fmaf(a4.x, fv, acc[j * 4 + 0]);
            acc[j * 4 + 1] = fmaf(a4.y, fv, acc[j * 4 + 1]);
            acc[j * 4 + 2] = fmaf(a4.z, fv, acc[j * 4 + 2]);
            acc[j * 4 + 3] = fmaf(a4.w, fv, acc[j * 4 + 3]);
        }
        acc[24] = fmaf(A_s[v][24], fv, acc[24]);
    }

    float* hp = h + (((size_t)n * C + c) * 25) * T + t;
#pragma unroll
    for (int w = 0; w < 25; ++w) hp[(size_t)w * T] = acc[w];
}

// ---------------------------------------------------------------------------
// conv-GEMM: dst[n][o][v][t'] = relu( sum_{i<C} sum_{k<TAPS}
//                 W[o][i][k] * src[n][i][v][t'*STRIDE + k - (TAPS-1)/2] )
// TAPS=1 -> 1x1 channel mix (W = ws, shape [M][C]); TAPS=9 -> temporal conv.
// Workgroup tile: 64 o x 8 t' x 25 v. 256 threads: (o_thr = tid&7, v = tid>>3).
// Per-thread microtile: 8 o x 8 t' with a per-lane register window over t
// reused across all taps (k) and output steps (tt).
// ---------------------------------------------------------------------------
template<int TAPS, int STRIDE, int WROW>
__global__ __launch_bounds__(WG)
void conv_gemm(const float* __restrict__ src, const float* __restrict__ W,
               float* __restrict__ dst, int C, int M, int Tin, int Tout)
{
    static_assert(WROW % 4 == 0, "window must be float4 sized");
    __shared__ __align__(16) float wt_s[CI * TAPS][68];
    __shared__ __align__(16) float g_s[CI * 25 * WROW];

    const int tid = threadIdx.x;
    const int t0 = blockIdx.x * 8;       // first output timestep of tile
    const int ot = blockIdx.y;           // o-tile (64 rows each)
    const int n  = blockIdx.z;
    const int PADT = (TAPS - 1) / 2;
    const int wstart = t0 * STRIDE - PADT;

    const float* srcn = src + (size_t)n * C * 25 * Tin;

    const int o_thr = tid & 7;
    const int v = tid >> 3;
    const bool active = (v < 25);

    float acc[8][8];
#pragma unroll
    for (int r = 0; r < 8; ++r)
#pragma unroll
        for (int tt = 0; tt < 8; ++tt) acc[r][tt] = 0.f;

    const int nchunk = (C + CI - 1) / CI;
    for (int ch = 0; ch < nchunk; ++ch) {
        const int i0 = ch * CI;
        // ---- stage W tile [CI*TAPS][64] (j = ii*TAPS+k fastest over tid) ----
        for (int idx = tid; idx < CI * TAPS * 64; idx += WG) {
            const int o  = idx / (CI * TAPS);
            const int j  = idx - o * (CI * TAPS);
            const int ii = j / TAPS;
            const int k  = j - ii * TAPS;
            const int ig = i0 + ii;
            float wv = 0.f;
            if (ig < C)
                wv = W[((size_t)(ot * 64 + o) * C + ig) * TAPS + k];
            wt_s[j][o] = wv;
        }
        // ---- stage src rows [CI][25][WROW] with zero-padded halo ----
        for (int idx = tid; idx < CI * 25; idx += WG) {
            const int ii = idx / 25;
            const int vv = idx - ii * 25;
            const int ig = i0 + ii;
            const float* rowp = srcn + ((size_t)ig * 25 + vv) * Tin;
            float* lrow = &g_s[idx * WROW];
            for (int j = 0; j < WROW; ++j) {
                const int tg = wstart + j;
                float val = 0.f;
                if (ig < C && tg >= 0 && tg < Tin) val = rowp[tg];
                lrow[j] = val;
            }
        }
        __syncthreads();

        if (active) {
#pragma unroll 2
            for (int ii = 0; ii < CI; ++ii) {
                float win[WROW];
                const float* grow = &g_s[(ii * 25 + v) * WROW];
#pragma unroll
                for (int ww = 0; ww < WROW / 4; ++ww) {
                    float4 t4 = *(const float4*)&grow[ww * 4];
                    win[ww * 4 + 0] = t4.x; win[ww * 4 + 1] = t4.y;
                    win[ww * 4 + 2] = t4.z; win[ww * 4 + 3] = t4.w;
                }
#pragma unroll
                for (int k = 0; k < TAPS; ++k) {
                    const float* arow = &wt_s[ii * TAPS + k][o_thr * 8];
                    float4 a0 = *(const float4*)&arow[0];
                    float4 a1 = *(const float4*)&arow[4];
                    float a[8] = { a0.x, a0.y, a0.z, a0.w,
                                   a1.x, a1.y, a1.z, a1.w };
#pragma unroll
                    for (int tt = 0; tt < 8; ++tt) {
                        const float b = win[k + tt * STRIDE];
#pragma unroll
                        for (int r = 0; r < 8; ++r)
                            acc[r][tt] = fmaf(a[r], b, acc[r][tt]);
                    }
                }
            }
        }
        __syncthreads();
    }

    if (active) {
        float* dstn = dst + (size_t)n * M * 25 * Tout;
#pragma unroll
        for (int r = 0; r < 8; ++r) {
            const int o = ot * 64 + o_thr * 8 + r;
            float* dp = dstn + ((size_t)o * 25 + v) * Tout;
#pragma unroll
            for (int tt = 0; tt < 8; ++tt) {
                const int t = t0 + tt;
                if (t < Tout) dp[t] = fmaxf(acc[r][tt], 0.f);
            }
        }
    }
}

// ---------------------------------------------------------------------------
// final layout fix: [n][256][25][75] (NCVT) -> [n][256][75][25] (NCTV)
// ---------------------------------------------------------------------------
__global__ __launch_bounds__(WG)
void transpose_vt(const float* __restrict__ in, float* __restrict__ out,
                  size_t total)
{
    size_t idx = (size_t)blockIdx.x * WG + threadIdx.x;
    if (idx >= total) return;
    const int v = (int)(idx % 25);
    size_t r = idx / 25;
    const int t = (int)(r % 75);
    size_t ct = r / 75;                  // ct = n*256 + c
    out[idx] = in[(ct * 25 + v) * 75 + t];
}

// ---------------------------------------------------------------------------

struct BlkCfg { int cin, cout, stride, Tin; };

extern "C" void kernel_launch(void* const* d_in, const int* in_sizes, int n_in,
                              void* d_out, int out_size, void* d_ws, size_t ws_size,
                              hipStream_t stream)
{
    const float* x = (const float*)d_in[0];
    const float* A = (const float*)d_in[1];
    const float* WS[10];
    const float* WT[10];
    for (int i = 0; i < 10; ++i) {
        WS[i] = (const float*)d_in[2 + 2 * i];
        WT[i] = (const float*)d_in[3 + 2 * i];
    }
    float* out = (float*)d_out;
    float* wsf = (float*)d_ws;

    static const BlkCfg cfg[10] = {
        {3, 64, 1, 300}, {64, 64, 1, 300}, {64, 64, 1, 300}, {64, 64, 1, 300},
        {64, 128, 2, 300}, {128, 128, 1, 150}, {128, 128, 1, 150},
        {128, 256, 2, 150}, {256, 256, 1, 75}, {256, 256, 1, 75}
    };

    // per-n buffer sizes (floats): f/h tensors are all <= 480000, g <= 960000
    const size_t FPN = 480000;
    const size_t GPN = 960000;
    const size_t perN = (2 * FPN + GPN) * sizeof(float);
    int NC = (int)(ws_size / perN);
    if (NC < 1) NC = 1;
    if (NC > 64) NC = 64;

    float* fA = wsf;                              // f between blocks
    float* hb = wsf + (size_t)NC * FPN;           // adjacency output
    float* gb = wsf + (size_t)NC * FPN * 2;       // spatial-GCN output

    for (int nb = 0; nb < 64; nb += NC) {
        const int nc = (64 - nb < NC) ? (64 - nb) : NC;
        for (int b = 0; b < 10; ++b) {
            const BlkCfg& c = cfg[b];
            const int Tout = (c.stride == 1) ? c.Tin : c.Tin / 2;

            // 1) adjacency multiply (commuted ahead of channel mix)
            dim3 ag((c.cin * c.Tin + WG - 1) / WG, nc);
            if (b == 0)
                adj_kernel<true><<<ag, WG, 0, stream>>>(
                    x + (size_t)nb * 22500, A, hb, c.cin, c.Tin);
            else
                adj_kernel<false><<<ag, WG, 0, stream>>>(
                    fA, A, hb, c.cin, c.Tin);

            // 2) 1x1 channel mix + relu
            dim3 cg((c.Tin + 7) / 8, c.cout / 64, nc);
            conv_gemm<1, 1, 8><<<cg, WG, 0, stream>>>(
                hb, WS[b], gb, c.cin, c.cout, c.Tin, c.Tin);

            // 3) 9-tap temporal conv + relu
            dim3 tg((Tout + 7) / 8, c.cout / 64, nc);
            if (c.stride == 1)
                conv_gemm<9, 1, 16><<<tg, WG, 0, stream>>>(
                    gb, WT[b], fA, c.cout, c.cout, c.Tin, Tout);
            else
                conv_gemm<9, 2, 24><<<tg, WG, 0, stream>>>(
                    gb, WT[b], fA, c.cout, c.cout, c.Tin, Tout);
        }
        // 4) NCVT -> NCTV into d_out
        const size_t tot = (size_t)nc * 256 * 75 * 25;
        transpose_vt<<<(unsigned)((tot + WG - 1) / WG), WG, 0, stream>>>(
            fA, out + (size_t)nb * 480000, tot);
    }
}

// Round 2
// 17196.530 us; speedup vs baseline: 1.1160x; 1.1160x over previous
//
#include <hip/hip_runtime.h>
#include <cstdint>

typedef unsigned short u16;
typedef unsigned int u32;
typedef __attribute__((ext_vector_type(8))) short short8v;
typedef __attribute__((ext_vector_type(4))) float float4v;

#define MFMA16 __builtin_amdgcn_mfma_f32_16x16x32_bf16

__device__ __forceinline__ u16 f2bf(float x) {
    union { float f; u32 u; } c; c.f = x;
    return (u16)((c.u + 0x7FFFu + ((c.u >> 16) & 1u)) >> 16);
}
__device__ __forceinline__ float bf2f(u16 h) {
    union { u32 u; float f; } c; c.u = ((u32)h) << 16;
    return c.f;
}

// ===================== weight prep =====================
// dst layout: [tap][ic][p][kg][M][8], value = split_p( W[m][ic*32+kg*8+j][tap] )
__global__ __launch_bounds__(256)
void prep_w(const float* __restrict__ W, u16* __restrict__ dst,
            int M, int cin, int nIC, int TAPS, int total)
{
    int e = blockIdx.x * 256 + threadIdx.x;
    if (e >= total) return;
    int tmp = e;
    int j = tmp & 7; tmp >>= 3;
    int m = tmp % M; tmp /= M;
    int kg = tmp & 3; tmp >>= 2;
    int p = tmp & 1; tmp >>= 1;
    int ic = tmp % nIC;
    int tap = tmp / nIC;
    int i = ic * 32 + kg * 8 + j;
    float val = (i < cin) ? W[((size_t)m * cin + i) * TAPS + tap] : 0.f;
    u16 h = f2bf(val);
    dst[e] = p ? f2bf(val - bf2f(h)) : h;
}

// ===================== adjacency: block 0 (from raw x) =====================
// x: [n][300][25][3] f32 -> h planes [25][300][32] (c>=3 zero), hi/lo
__global__ __launch_bounds__(256)
void adj0(const float* __restrict__ x, const float* __restrict__ Am,
          u16* __restrict__ dstb, long dst_nstride, int dst_poff)
{
    __shared__ float A_s[25][26];
    for (int i2 = threadIdx.x; i2 < 625; i2 += 256) A_s[i2 / 25][i2 % 25] = Am[i2];
    __syncthreads();
    int t = blockIdx.x * 256 + threadIdx.x;
    int nl = blockIdx.y;
    if (t >= 300) return;
    const float* xp = x + ((size_t)nl * 300 + t) * 75;
    float acc[25][3];
#pragma unroll
    for (int w = 0; w < 25; ++w) { acc[w][0] = 0.f; acc[w][1] = 0.f; acc[w][2] = 0.f; }
    for (int v = 0; v < 25; ++v) {
        float x0 = xp[v * 3 + 0], x1 = xp[v * 3 + 1], x2 = xp[v * 3 + 2];
#pragma unroll
        for (int w = 0; w < 25; ++w) {
            float a = A_s[v][w];
            acc[w][0] = fmaf(a, x0, acc[w][0]);
            acc[w][1] = fmaf(a, x1, acc[w][1]);
            acc[w][2] = fmaf(a, x2, acc[w][2]);
        }
    }
    u16* dhi = dstb + (size_t)nl * dst_nstride;
    u16* dlo = dhi + dst_poff;
#pragma unroll
    for (int w = 0; w < 25; ++w) {
        u16 hb[32], lb[32];
#pragma unroll
        for (int c = 0; c < 32; ++c) { hb[c] = 0; lb[c] = 0; }
#pragma unroll
        for (int c = 0; c < 3; ++c) {
            float y = acc[w][c];
            u16 h = f2bf(y);
            hb[c] = h; lb[c] = f2bf(y - bf2f(h));
        }
        size_t o = ((size_t)w * 300 + t) * 32;
#pragma unroll
        for (int q = 0; q < 4; ++q) {
            *(uint4*)&dhi[o + q * 8] = *(const uint4*)&hb[q * 8];
            *(uint4*)&dlo[o + q * 8] = *(const uint4*)&lb[q * 8];
        }
    }
}

// ===================== adjacency: general =====================
// h[w][t][c] = sum_v A[v][w] * f[v][t][c]   (hi/lo planes in and out)
__global__ __launch_bounds__(256)
void adj_mm(const u16* __restrict__ srcb, const float* __restrict__ Am,
            u16* __restrict__ dstb, int C, int T,
            long src_nstride, int src_poff, long dst_nstride, int dst_poff)
{
    __shared__ float A_s[25][26];
    for (int i2 = threadIdx.x; i2 < 625; i2 += 256) A_s[i2 / 25][i2 % 25] = Am[i2];
    __syncthreads();
    int nl = blockIdx.y;
    int C4 = C >> 2;
    int idx = blockIdx.x * 256 + threadIdx.x;
    if (idx >= T * C4) return;
    int t = idx / C4;
    int c4 = (idx - t * C4) * 4;
    const u16* shi = srcb + (size_t)nl * src_nstride;
    const u16* slo = shi + src_poff;
    float acc[25][4];
#pragma unroll
    for (int w = 0; w < 25; ++w)
#pragma unroll
        for (int j = 0; j < 4; ++j) acc[w][j] = 0.f;
    for (int v = 0; v < 25; ++v) {
        size_t o = ((size_t)(v * T + t)) * C + c4;
        ushort4 h4 = *(const ushort4*)&shi[o];
        ushort4 l4 = *(const ushort4*)&slo[o];
        float x0 = bf2f(h4.x) + bf2f(l4.x);
        float x1 = bf2f(h4.y) + bf2f(l4.y);
        float x2 = bf2f(h4.z) + bf2f(l4.z);
        float x3 = bf2f(h4.w) + bf2f(l4.w);
#pragma unroll
        for (int w = 0; w < 25; ++w) {
            float a = A_s[v][w];
            acc[w][0] = fmaf(a, x0, acc[w][0]);
            acc[w][1] = fmaf(a, x1, acc[w][1]);
            acc[w][2] = fmaf(a, x2, acc[w][2]);
            acc[w][3] = fmaf(a, x3, acc[w][3]);
        }
    }
    u16* dhi = dstb + (size_t)nl * dst_nstride;
    u16* dlo = dhi + dst_poff;
#pragma unroll
    for (int w = 0; w < 25; ++w) {
        ushort4 ho, lo;
        float y;
        u16 h;
        y = fmaxf(acc[w][0], acc[w][0]); h = f2bf(y); ho.x = h; lo.x = f2bf(y - bf2f(h));
        y = acc[w][1]; h = f2bf(y); ho.y = h; lo.y = f2bf(y - bf2f(h));
        y = acc[w][2]; h = f2bf(y); ho.z = h; lo.z = f2bf(y - bf2f(h));
        y = acc[w][3]; h = f2bf(y); ho.w = h; lo.w = f2bf(y - bf2f(h));
        size_t o = ((size_t)(w * T + t)) * C + c4;
        *(ushort4*)&dhi[o] = ho;
        *(ushort4*)&dlo[o] = lo;
    }
}

// ===================== conv-GEMM via MFMA (split bf16) =====================
// dst[o][v][t'] = relu( sum_{i,k} W[o][i][k] * src[i][v][t'*S + k - PAD] )
// A (weights) from prep buffer, B (acts) staged per 32-ch chunk, reused over taps.
template<int MW, int NW, int NT, int TAPS, int S>
__global__ __launch_bounds__(256)
void conv_mfma(const u16* __restrict__ srcb, const u16* __restrict__ wtp,
               u16* __restrict__ dstb, int C, int Tin, int Tout,
               long src_nstride, int src_poff, long dst_nstride, int dst_poff)
{
    constexpr int M = MW * 64;
    constexpr int Nt = NT / 16;
    constexpr int PADW = (TAPS == 1) ? 0 : 4;
    constexpr int WIN = (TAPS == 1) ? (NW * NT) : (NW * NT * S + 8);
    constexpr int BP = 40;                    // B row pitch (ushorts)
    constexpr int A_USH = 64 * M;             // per (tap,ic) tile, ushorts
    constexpr int A_BYTES = A_USH * 2;
    constexpr int B_BYTES = 2 * WIN * BP * 2;
    constexpr int EP = M + 2;
    constexpr int E_BYTES = NW * 16 * EP * 4;
    constexpr int SMEM = A_BYTES + (B_BYTES > E_BYTES ? B_BYTES : E_BYTES);
    __shared__ __align__(16) char smem[SMEM];
    u16* As = (u16*)smem;
    u16* Bs = (u16*)(smem + A_BYTES);
    float* E = (float*)(smem + A_BYTES);

    const int tid = threadIdx.x;
    const int l = tid & 63;
    const int w = tid >> 6;
    const int wm = w % MW;
    const int wn = w / MW;
    const int l15 = l & 15;
    const int lkg = l >> 4;

    const int strip = blockIdx.x / 25;
    const int v = blockIdx.x % 25;
    const int nl = blockIdx.z;
    const int t0 = strip * (NW * NT);
    const int wstart = t0 * S - PADW;

    const u16* shi = srcb + (size_t)nl * src_nstride;
    const u16* slo = shi + src_poff;

    float4v acc[4][Nt];
#pragma unroll
    for (int mt = 0; mt < 4; ++mt)
#pragma unroll
        for (int nf = 0; nf < Nt; ++nf) acc[mt][nf] = (float4v)0.f;

    const int nIC = C >> 5;
#pragma unroll 1
    for (int ic = 0; ic < nIC; ++ic) {
        const int i0 = ic * 32;
        // ---- stage B window (hi+lo), 16B chunks (pad slot untouched) ----
        {
            const int CH = 2 * WIN * 4;
            for (int q = tid; q < CH; q += 256) {
                const int p = q / (WIN * 4);
                const int rem = q - p * (WIN * 4);
                const int row = rem >> 2;
                const int part = rem & 3;
                const int t = wstart + row;
                uint4 val = {0u, 0u, 0u, 0u};
                if (t >= 0 && t < Tin) {
                    const u16* sp = (p ? slo : shi) + ((size_t)(v * Tin + t)) * C + i0 + part * 8;
                    val = *(const uint4*)sp;
                }
                *(uint4*)&Bs[(p * WIN + row) * BP + part * 8] = val;
            }
        }
#pragma unroll 1
        for (int tap = 0; tap < TAPS; ++tap) {
            // ---- stage A tile: linear copy from prep ----
            {
                const u16* at = wtp + (size_t)(tap * nIC + ic) * A_USH;
                const int CHA = A_USH / 8;
                for (int q = tid; q < CHA; q += 256)
                    *(uint4*)&As[q * 8] = *(const uint4*)&at[q * 8];
            }
            __syncthreads();
            short8v ah[4], al[4], bh[Nt], bl[Nt];
            const int mb = wm * 64 + l15;
#pragma unroll
            for (int mt = 0; mt < 4; ++mt) {
                ah[mt] = *(const short8v*)&As[((0 + lkg) * M + mb + mt * 16) * 8];
                al[mt] = *(const short8v*)&As[((4 + lkg) * M + mb + mt * 16) * 8];
            }
#pragma unroll
            for (int nf = 0; nf < Nt; ++nf) {
                const int row = (wn * NT + nf * 16 + l15) * S + tap;
                bh[nf] = *(const short8v*)&Bs[(0 * WIN + row) * BP + lkg * 8];
                bl[nf] = *(const short8v*)&Bs[(1 * WIN + row) * BP + lkg * 8];
            }
#pragma unroll
            for (int mt = 0; mt < 4; ++mt)
#pragma unroll
                for (int nf = 0; nf < Nt; ++nf) {
                    acc[mt][nf] = MFMA16(ah[mt], bh[nf], acc[mt][nf], 0, 0, 0);
                    acc[mt][nf] = MFMA16(ah[mt], bl[nf], acc[mt][nf], 0, 0, 0);
                    acc[mt][nf] = MFMA16(al[mt], bh[nf], acc[mt][nf], 0, 0, 0);
                }
            __syncthreads();
        }
    }

    // ---- epilogue: LDS transpose per 16-t' slice, relu, split, coalesced store ----
    u16* dhi = dstb + (size_t)nl * dst_nstride;
    u16* dlo = dhi + dst_poff;
    const int tpr = M / 16;
    const int rowid = tid / tpr;
    const int cblk = tid % tpr;
#pragma unroll 1
    for (int nf = 0; nf < Nt; ++nf) {
#pragma unroll
        for (int mt = 0; mt < 4; ++mt)
#pragma unroll
            for (int r = 0; r < 4; ++r)
                E[(wn * 16 + l15) * EP + wm * 64 + mt * 16 + lkg * 4 + r] = acc[mt][nf][r];
        __syncthreads();
        const int wn2 = rowid >> 4;
        const int tl = rowid & 15;
        const int tg = t0 + wn2 * NT + nf * 16 + tl;
        if (tg < Tout) {
            u16 hb[16], lb[16];
#pragma unroll
            for (int j = 0; j < 16; ++j) {
                float y = fmaxf(E[rowid * EP + cblk * 16 + j], 0.f);
                u16 h = f2bf(y);
                hb[j] = h;
                lb[j] = f2bf(y - bf2f(h));
            }
            size_t o = ((size_t)(v * Tout + tg)) * M + cblk * 16;
            *(uint4*)&dhi[o] = *(const uint4*)&hb[0];
            *(uint4*)&dhi[o + 8] = *(const uint4*)&hb[8];
            *(uint4*)&dlo[o] = *(const uint4*)&lb[0];
            *(uint4*)&dlo[o + 8] = *(const uint4*)&lb[8];
        }
        __syncthreads();
    }
}

// ===================== final transpose: [v][t][c] -> out[n][c][t][v] f32 =====================
__global__ __launch_bounds__(256)
void out_tr(const u16* __restrict__ fb, float* __restrict__ out,
            long src_nstride, int src_poff)
{
    __shared__ float S[25 * 257];
    int t = blockIdx.x;
    int nl = blockIdx.y;
    const u16* hi = fb + (size_t)nl * src_nstride;
    const u16* lo = hi + src_poff;
    int c = threadIdx.x;
#pragma unroll
    for (int v = 0; v < 25; ++v) {
        size_t o = ((size_t)(v * 75 + t)) * 256 + c;
        S[v * 257 + c] = bf2f(hi[o]) + bf2f(lo[o]);
    }
    __syncthreads();
    float* op = out + (size_t)nl * 480000 + (size_t)c * 1875 + t * 25;
#pragma unroll
    for (int v = 0; v < 25; ++v) op[v] = S[v * 257 + c];
}

// ===================== host =====================
struct Cfg { int cin, cout, stride, Tin; };

extern "C" void kernel_launch(void* const* d_in, const int* in_sizes, int n_in,
                              void* d_out, int out_size, void* d_ws, size_t ws_size,
                              hipStream_t stream)
{
    const float* x = (const float*)d_in[0];
    const float* A = (const float*)d_in[1];
    const float* WS[10];
    const float* WT[10];
    for (int i = 0; i < 10; ++i) {
        WS[i] = (const float*)d_in[2 + 2 * i];
        WT[i] = (const float*)d_in[3 + 2 * i];
    }
    float* out = (float*)d_out;

    static const Cfg cfg[10] = {
        {3, 64, 1, 300}, {64, 64, 1, 300}, {64, 64, 1, 300}, {64, 64, 1, 300},
        {64, 128, 2, 300}, {128, 128, 1, 150}, {128, 128, 1, 150},
        {128, 256, 2, 150}, {256, 256, 1, 75}, {256, 256, 1, 75}
    };

    // ---- prep buffer layout ----
    size_t mixoff[10], wtoff[10], off = 0;
    int cinp[10];
    for (int b = 0; b < 10; ++b) {
        int M = cfg[b].cout;
        cinp[b] = (b == 0) ? 32 : cfg[b].cin;
        mixoff[b] = off; off += (size_t)(cinp[b] / 32) * 64 * M;
        wtoff[b] = off;  off += (size_t)9 * (M / 32) * 64 * M;
    }
    u16* prep = (u16*)d_ws;
    size_t prep_bytes = ((off * 2 + 255) / 256) * 256;
    u16* bufs = (u16*)((char*)d_ws + prep_bytes);

    const long PER_N = 3840000;   // ushorts per n: fA(2x480000) h(2x480000) g(2x960000)
    const int FA = 0, HB = 960000, GB = 1920000;

    int NC = (int)((ws_size - prep_bytes) / ((size_t)PER_N * 2));
    if (NC < 1) NC = 1;
    if (NC > 64) NC = 64;

    // ---- weight prep (once per call) ----
    for (int b = 0; b < 10; ++b) {
        int M = cfg[b].cout;
        int nICm = cinp[b] / 32;
        int totm = nICm * 64 * M;
        prep_w<<<(totm + 255) / 256, 256, 0, stream>>>(WS[b], prep + mixoff[b], M, cfg[b].cin, nICm, 1, totm);
        int nICt = M / 32;
        int tott = 9 * nICt * 64 * M;
        prep_w<<<(tott + 255) / 256, 256, 0, stream>>>(WT[b], prep + wtoff[b], M, M, nICt, 9, tott);
    }

    for (int nb = 0; nb < 64; nb += NC) {
        const int nc = (64 - nb < NC) ? (64 - nb) : NC;
        for (int b = 0; b < 10; ++b) {
            const Cfg& c = cfg[b];
            const int Tin = c.Tin;
            const int Tout = (c.stride == 1) ? Tin : Tin / 2;
            // 1) adjacency
            if (b == 0) {
                adj0<<<dim3(2, nc), 256, 0, stream>>>(x + (size_t)nb * 22500, A,
                                                      bufs + HB, PER_N, 480000);
            } else {
                int gx = (Tin * (c.cin / 4) + 255) / 256;
                adj_mm<<<dim3(gx, nc), 256, 0, stream>>>(bufs + FA, A, bufs + HB,
                                                         c.cin, Tin, PER_N, 480000, PER_N, 480000);
            }
            // 2) channel mix (TAPS=1) : h -> g
            {
                int span = (c.cout == 64) ? 320 : (c.cout == 128) ? 160 : 80;
                int ts = (Tin + span - 1) / span;
                dim3 g(25 * ts, 1, nc);
                if (c.cout == 64)
                    conv_mfma<1, 4, 80, 1, 1><<<g, 256, 0, stream>>>(bufs + HB, prep + mixoff[b], bufs + GB,
                        cinp[b], Tin, Tin, PER_N, 480000, PER_N, 960000);
                else if (c.cout == 128)
                    conv_mfma<2, 2, 80, 1, 1><<<g, 256, 0, stream>>>(bufs + HB, prep + mixoff[b], bufs + GB,
                        cinp[b], Tin, Tin, PER_N, 480000, PER_N, 960000);
                else
                    conv_mfma<4, 1, 80, 1, 1><<<g, 256, 0, stream>>>(bufs + HB, prep + mixoff[b], bufs + GB,
                        cinp[b], Tin, Tin, PER_N, 480000, PER_N, 960000);
            }
            // 3) temporal conv (TAPS=9) : g -> fA
            {
                if (b <= 3) {
                    conv_mfma<1, 4, 80, 9, 1><<<dim3(25, 1, nc), 256, 0, stream>>>(bufs + GB, prep + wtoff[b], bufs + FA,
                        c.cout, Tin, Tout, PER_N, 960000, PER_N, 480000);
                } else if (b == 4) {
                    conv_mfma<2, 2, 64, 9, 2><<<dim3(50, 1, nc), 256, 0, stream>>>(bufs + GB, prep + wtoff[b], bufs + FA,
                        c.cout, Tin, Tout, PER_N, 960000, PER_N, 480000);
                } else if (b <= 6) {
                    conv_mfma<2, 2, 80, 9, 1><<<dim3(25, 1, nc), 256, 0, stream>>>(bufs + GB, prep + wtoff[b], bufs + FA,
                        c.cout, Tin, Tout, PER_N, 960000, PER_N, 480000);
                } else if (b == 7) {
                    conv_mfma<4, 1, 80, 9, 2><<<dim3(25, 1, nc), 256, 0, stream>>>(bufs + GB, prep + wtoff[b], bufs + FA,
                        c.cout, Tin, Tout, PER_N, 960000, PER_N, 480000);
                } else {
                    conv_mfma<4, 1, 80, 9, 1><<<dim3(25, 1, nc), 256, 0, stream>>>(bufs + GB, prep + wtoff[b], bufs + FA,
                        c.cout, Tin, Tout, PER_N, 960000, PER_N, 480000);
                }
            }
        }
        // 4) final transpose to NCTV f32
        out_tr<<<dim3(75, nc), 256, 0, stream>>>(bufs + FA, out + (size_t)nb * 480000, PER_N, 480000);
    }
}

// Round 3
// 8059.882 us; speedup vs baseline: 2.3812x; 2.1336x over previous
//
#include <hip/hip_runtime.h>
#include <cstdint>

typedef unsigned short u16;
typedef unsigned int u32;
typedef __attribute__((ext_vector_type(8))) short short8v;
typedef __attribute__((ext_vector_type(4))) float float4v;

#define MFMA16 __builtin_amdgcn_mfma_f32_16x16x32_bf16

__device__ __forceinline__ u16 f2bf(float x) {
    union { float f; u32 u; } c; c.f = x;
    return (u16)((c.u + 0x7FFFu + ((c.u >> 16) & 1u)) >> 16);
}
__device__ __forceinline__ float bf2f(u16 h) {
    union { u32 u; float f; } c; c.u = ((u32)h) << 16;
    return c.f;
}

// ===================== weight prep =====================
// dst layout: [tap][ic][p][kg][M][8], value = split_p( W[m][ic*32+kg*8+j][tap] )
__global__ __launch_bounds__(256)
void prep_w(const float* __restrict__ W, u16* __restrict__ dst,
            int M, int cin, int nIC, int TAPS, int total)
{
    int e = blockIdx.x * 256 + threadIdx.x;
    if (e >= total) return;
    int tmp = e;
    int j = tmp & 7; tmp >>= 3;
    int m = tmp % M; tmp /= M;
    int kg = tmp & 3; tmp >>= 2;
    int p = tmp & 1; tmp >>= 1;
    int ic = tmp % nIC;
    int tap = tmp / nIC;
    int i = ic * 32 + kg * 8 + j;
    float val = (i < cin) ? W[((size_t)m * cin + i) * TAPS + tap] : 0.f;
    u16 h = f2bf(val);
    dst[e] = p ? f2bf(val - bf2f(h)) : h;
}

// ===================== adjacency: block 0 (from raw x) =====================
// x: [n][300][25][3] f32 -> h planes [25][300][32] (c>=3 zero), hi/lo
__global__ __launch_bounds__(256)
void adj0(const float* __restrict__ x, const float* __restrict__ Am,
          u16* __restrict__ dstb, long dst_nstride, int dst_poff)
{
    __shared__ float A_s[25][26];
    for (int i2 = threadIdx.x; i2 < 625; i2 += 256) A_s[i2 / 25][i2 % 25] = Am[i2];
    __syncthreads();
    int t = blockIdx.x * 256 + threadIdx.x;
    int nl = blockIdx.y;
    if (t >= 300) return;
    const float* xp = x + ((size_t)nl * 300 + t) * 75;
    float acc[25][3];
#pragma unroll
    for (int w = 0; w < 25; ++w) { acc[w][0] = 0.f; acc[w][1] = 0.f; acc[w][2] = 0.f; }
    for (int v = 0; v < 25; ++v) {
        float x0 = xp[v * 3 + 0], x1 = xp[v * 3 + 1], x2 = xp[v * 3 + 2];
#pragma unroll
        for (int w = 0; w < 25; ++w) {
            float a = A_s[v][w];
            acc[w][0] = fmaf(a, x0, acc[w][0]);
            acc[w][1] = fmaf(a, x1, acc[w][1]);
            acc[w][2] = fmaf(a, x2, acc[w][2]);
        }
    }
    u16* dhi = dstb + (size_t)nl * dst_nstride;
    u16* dlo = dhi + dst_poff;
#pragma unroll
    for (int w = 0; w < 25; ++w) {
        u16 hb[32], lb[32];
#pragma unroll
        for (int c = 0; c < 32; ++c) { hb[c] = 0; lb[c] = 0; }
#pragma unroll
        for (int c = 0; c < 3; ++c) {
            float y = acc[w][c];
            u16 h = f2bf(y);
            hb[c] = h; lb[c] = f2bf(y - bf2f(h));
        }
        size_t o = ((size_t)w * 300 + t) * 32;
#pragma unroll
        for (int q = 0; q < 4; ++q) {
            *(uint4*)&dhi[o + q * 8] = *(const uint4*)&hb[q * 8];
            *(uint4*)&dlo[o + q * 8] = *(const uint4*)&lb[q * 8];
        }
    }
}

// ===================== adjacency: general =====================
// h[w][t][c] = sum_v A[v][w] * f[v][t][c]   (hi/lo planes in and out)
__global__ __launch_bounds__(256)
void adj_mm(const u16* __restrict__ srcb, const float* __restrict__ Am,
            u16* __restrict__ dstb, int C, int T,
            long src_nstride, int src_poff, long dst_nstride, int dst_poff)
{
    __shared__ float A_s[25][26];
    for (int i2 = threadIdx.x; i2 < 625; i2 += 256) A_s[i2 / 25][i2 % 25] = Am[i2];
    __syncthreads();
    int nl = blockIdx.y;
    int C4 = C >> 2;
    int idx = blockIdx.x * 256 + threadIdx.x;
    if (idx >= T * C4) return;
    int t = idx / C4;
    int c4 = (idx - t * C4) * 4;
    const u16* shi = srcb + (size_t)nl * src_nstride;
    const u16* slo = shi + src_poff;
    float acc[25][4];
#pragma unroll
    for (int w = 0; w < 25; ++w)
#pragma unroll
        for (int j = 0; j < 4; ++j) acc[w][j] = 0.f;
    for (int v = 0; v < 25; ++v) {
        size_t o = ((size_t)(v * T + t)) * C + c4;
        ushort4 h4 = *(const ushort4*)&shi[o];
        ushort4 l4 = *(const ushort4*)&slo[o];
        float x0 = bf2f(h4.x) + bf2f(l4.x);
        float x1 = bf2f(h4.y) + bf2f(l4.y);
        float x2 = bf2f(h4.z) + bf2f(l4.z);
        float x3 = bf2f(h4.w) + bf2f(l4.w);
#pragma unroll
        for (int w = 0; w < 25; ++w) {
            float a = A_s[v][w];
            acc[w][0] = fmaf(a, x0, acc[w][0]);
            acc[w][1] = fmaf(a, x1, acc[w][1]);
            acc[w][2] = fmaf(a, x2, acc[w][2]);
            acc[w][3] = fmaf(a, x3, acc[w][3]);
        }
    }
    u16* dhi = dstb + (size_t)nl * dst_nstride;
    u16* dlo = dhi + dst_poff;
#pragma unroll
    for (int w = 0; w < 25; ++w) {
        ushort4 ho, lo;
        float y;
        u16 h;
        y = fmaxf(acc[w][0], acc[w][0]); h = f2bf(y); ho.x = h; lo.x = f2bf(y - bf2f(h));
        y = acc[w][1]; h = f2bf(y); ho.y = h; lo.y = f2bf(y - bf2f(h));
        y = acc[w][2]; h = f2bf(y); ho.z = h; lo.z = f2bf(y - bf2f(h));
        y = acc[w][3]; h = f2bf(y); ho.w = h; lo.w = f2bf(y - bf2f(h));
        size_t o = ((size_t)(w * T + t)) * C + c4;
        *(ushort4*)&dhi[o] = ho;
        *(ushort4*)&dlo[o] = lo;
    }
}

// ===================== conv-GEMM via MFMA (split bf16) =====================
// dst[o][v][t'] = relu( sum_{i,k} W[o][i][k] * src[i][v][t'*S + k - PAD] )
// A (weights) from prep buffer, B (acts) staged per 32-ch chunk, reused over taps.
template<int MW, int NW, int NT, int TAPS, int S>
__global__ __launch_bounds__(256)
void conv_mfma(const u16* __restrict__ srcb, const u16* __restrict__ wtp,
               u16* __restrict__ dstb, int C, int Tin, int Tout,
               long src_nstride, int src_poff, long dst_nstride, int dst_poff)
{
    constexpr int M = MW * 64;
    constexpr int Nt = NT / 16;
    constexpr int PADW = (TAPS == 1) ? 0 : 4;
    constexpr int WIN = (TAPS == 1) ? (NW * NT) : (NW * NT * S + 8);
    constexpr int BP = 40;                    // B row pitch (ushorts)
    constexpr int A_USH = 64 * M;             // per (tap,ic) tile, ushorts
    constexpr int A_BYTES = A_USH * 2;
    constexpr int B_BYTES = 2 * WIN * BP * 2;
    constexpr int EP = M + 2;
    constexpr int E_BYTES = NW * 16 * EP * 4;
    constexpr int SMEM = A_BYTES + (B_BYTES > E_BYTES ? B_BYTES : E_BYTES);
    __shared__ __align__(16) char smem[SMEM];
    u16* As = (u16*)smem;
    u16* Bs = (u16*)(smem + A_BYTES);
    float* E = (float*)(smem + A_BYTES);

    const int tid = threadIdx.x;
    const int l = tid & 63;
    const int w = tid >> 6;
    const int wm = w % MW;
    const int wn = w / MW;
    const int l15 = l & 15;
    const int lkg = l >> 4;

    const int strip = blockIdx.x / 25;
    const int v = blockIdx.x % 25;
    const int nl = blockIdx.z;
    const int t0 = strip * (NW * NT);
    const int wstart = t0 * S - PADW;

    const u16* shi = srcb + (size_t)nl * src_nstride;
    const u16* slo = shi + src_poff;

    float4v acc[4][Nt];
#pragma unroll
    for (int mt = 0; mt < 4; ++mt)
#pragma unroll
        for (int nf = 0; nf < Nt; ++nf) acc[mt][nf] = (float4v)0.f;

    const int nIC = C >> 5;
#pragma unroll 1
    for (int ic = 0; ic < nIC; ++ic) {
        const int i0 = ic * 32;
        // ---- stage B window (hi+lo), 16B chunks (pad slot untouched) ----
        {
            const int CH = 2 * WIN * 4;
            for (int q = tid; q < CH; q += 256) {
                const int p = q / (WIN * 4);
                const int rem = q - p * (WIN * 4);
                const int row = rem >> 2;
                const int part = rem & 3;
                const int t = wstart + row;
                uint4 val = {0u, 0u, 0u, 0u};
                if (t >= 0 && t < Tin) {
                    const u16* sp = (p ? slo : shi) + ((size_t)(v * Tin + t)) * C + i0 + part * 8;
                    val = *(const uint4*)sp;
                }
                *(uint4*)&Bs[(p * WIN + row) * BP + part * 8] = val;
            }
        }
#pragma unroll 1
        for (int tap = 0; tap < TAPS; ++tap) {
            // ---- stage A tile: linear copy from prep ----
            {
                const u16* at = wtp + (size_t)(tap * nIC + ic) * A_USH;
                const int CHA = A_USH / 8;
                for (int q = tid; q < CHA; q += 256)
                    *(uint4*)&As[q * 8] = *(const uint4*)&at[q * 8];
            }
            __syncthreads();
            short8v ah[4], al[4], bh[Nt], bl[Nt];
            const int mb = wm * 64 + l15;
#pragma unroll
            for (int mt = 0; mt < 4; ++mt) {
                ah[mt] = *(const short8v*)&As[((0 + lkg) * M + mb + mt * 16) * 8];
                al[mt] = *(const short8v*)&As[((4 + lkg) * M + mb + mt * 16) * 8];
            }
#pragma unroll
            for (int nf = 0; nf < Nt; ++nf) {
                const int row = (wn * NT + nf * 16 + l15) * S + tap;
                bh[nf] = *(const short8v*)&Bs[(0 * WIN + row) * BP + lkg * 8];
                bl[nf] = *(const short8v*)&Bs[(1 * WIN + row) * BP + lkg * 8];
            }
#pragma unroll
            for (int mt = 0; mt < 4; ++mt)
#pragma unroll
                for (int nf = 0; nf < Nt; ++nf) {
                    acc[mt][nf] = MFMA16(ah[mt], bh[nf], acc[mt][nf], 0, 0, 0);
                    acc[mt][nf] = MFMA16(ah[mt], bl[nf], acc[mt][nf], 0, 0, 0);
                    acc[mt][nf] = MFMA16(al[mt], bh[nf], acc[mt][nf], 0, 0, 0);
                }
            __syncthreads();
        }
    }

    // ---- epilogue: LDS transpose per 16-t' slice, relu, split, coalesced store ----
    // NOTE: fully unrolled over nf — runtime-indexed acc[][] would force the
    // whole accumulator to scratch (rule #20; round-2 showed 9 GB spill writes).
    u16* dhi = dstb + (size_t)nl * dst_nstride;
    u16* dlo = dhi + dst_poff;
    const int tpr = M / 16;
    const int rowid = tid / tpr;
    const int cblk = tid % tpr;
#pragma unroll
    for (int nf = 0; nf < Nt; ++nf) {
#pragma unroll
        for (int mt = 0; mt < 4; ++mt)
#pragma unroll
            for (int r = 0; r < 4; ++r)
                E[(wn * 16 + l15) * EP + wm * 64 + mt * 16 + lkg * 4 + r] = acc[mt][nf][r];
        __syncthreads();
        const int wn2 = rowid >> 4;
        const int tl = rowid & 15;
        const int tg = t0 + wn2 * NT + nf * 16 + tl;
        if (tg < Tout) {
            u16 hb[16], lb[16];
#pragma unroll
            for (int j = 0; j < 16; ++j) {
                float y = fmaxf(E[rowid * EP + cblk * 16 + j], 0.f);
                u16 h = f2bf(y);
                hb[j] = h;
                lb[j] = f2bf(y - bf2f(h));
            }
            size_t o = ((size_t)(v * Tout + tg)) * M + cblk * 16;
            *(uint4*)&dhi[o] = *(const uint4*)&hb[0];
            *(uint4*)&dhi[o + 8] = *(const uint4*)&hb[8];
            *(uint4*)&dlo[o] = *(const uint4*)&lb[0];
            *(uint4*)&dlo[o + 8] = *(const uint4*)&lb[8];
        }
        __syncthreads();
    }
}

// ===================== final transpose: [v][t][c] -> out[n][c][t][v] f32 =====================
__global__ __launch_bounds__(256)
void out_tr(const u16* __restrict__ fb, float* __restrict__ out,
            long src_nstride, int src_poff)
{
    __shared__ float S[25 * 257];
    int t = blockIdx.x;
    int nl = blockIdx.y;
    const u16* hi = fb + (size_t)nl * src_nstride;
    const u16* lo = hi + src_poff;
    int c = threadIdx.x;
#pragma unroll
    for (int v = 0; v < 25; ++v) {
        size_t o = ((size_t)(v * 75 + t)) * 256 + c;
        S[v * 257 + c] = bf2f(hi[o]) + bf2f(lo[o]);
    }
    __syncthreads();
    float* op = out + (size_t)nl * 480000 + (size_t)c * 1875 + t * 25;
#pragma unroll
    for (int v = 0; v < 25; ++v) op[v] = S[v * 257 + c];
}

// ===================== host =====================
struct Cfg { int cin, cout, stride, Tin; };

extern "C" void kernel_launch(void* const* d_in, const int* in_sizes, int n_in,
                              void* d_out, int out_size, void* d_ws, size_t ws_size,
                              hipStream_t stream)
{
    const float* x = (const float*)d_in[0];
    const float* A = (const float*)d_in[1];
    const float* WS[10];
    const float* WT[10];
    for (int i = 0; i < 10; ++i) {
        WS[i] = (const float*)d_in[2 + 2 * i];
        WT[i] = (const float*)d_in[3 + 2 * i];
    }
    float* out = (float*)d_out;

    static const Cfg cfg[10] = {
        {3, 64, 1, 300}, {64, 64, 1, 300}, {64, 64, 1, 300}, {64, 64, 1, 300},
        {64, 128, 2, 300}, {128, 128, 1, 150}, {128, 128, 1, 150},
        {128, 256, 2, 150}, {256, 256, 1, 75}, {256, 256, 1, 75}
    };

    // ---- prep buffer layout ----
    size_t mixoff[10], wtoff[10], off = 0;
    int cinp[10];
    for (int b = 0; b < 10; ++b) {
        int M = cfg[b].cout;
        cinp[b] = (b == 0) ? 32 : cfg[b].cin;
        mixoff[b] = off; off += (size_t)(cinp[b] / 32) * 64 * M;
        wtoff[b] = off;  off += (size_t)9 * (M / 32) * 64 * M;
    }
    u16* prep = (u16*)d_ws;
    size_t prep_bytes = ((off * 2 + 255) / 256) * 256;
    u16* bufs = (u16*)((char*)d_ws + prep_bytes);

    const long PER_N = 3840000;   // ushorts per n: fA(2x480000) h(2x480000) g(2x960000)
    const int FA = 0, HB = 960000, GB = 1920000;

    int NC = (int)((ws_size - prep_bytes) / ((size_t)PER_N * 2));
    if (NC < 1) NC = 1;
    if (NC > 64) NC = 64;

    // ---- weight prep (once per call) ----
    for (int b = 0; b < 10; ++b) {
        int M = cfg[b].cout;
        int nICm = cinp[b] / 32;
        int totm = nICm * 64 * M;
        prep_w<<<(totm + 255) / 256, 256, 0, stream>>>(WS[b], prep + mixoff[b], M, cfg[b].cin, nICm, 1, totm);
        int nICt = M / 32;
        int tott = 9 * nICt * 64 * M;
        prep_w<<<(tott + 255) / 256, 256, 0, stream>>>(WT[b], prep + wtoff[b], M, M, nICt, 9, tott);
    }

    for (int nb = 0; nb < 64; nb += NC) {
        const int nc = (64 - nb < NC) ? (64 - nb) : NC;
        for (int b = 0; b < 10; ++b) {
            const Cfg& c = cfg[b];
            const int Tin = c.Tin;
            const int Tout = (c.stride == 1) ? Tin : Tin / 2;
            // 1) adjacency
            if (b == 0) {
                adj0<<<dim3(2, nc), 256, 0, stream>>>(x + (size_t)nb * 22500, A,
                                                      bufs + HB, PER_N, 480000);
            } else {
                int gx = (Tin * (c.cin / 4) + 255) / 256;
                adj_mm<<<dim3(gx, nc), 256, 0, stream>>>(bufs + FA, A, bufs + HB,
                                                         c.cin, Tin, PER_N, 480000, PER_N, 480000);
            }
            // 2) channel mix (TAPS=1) : h -> g
            {
                int span = (c.cout == 64) ? 320 : (c.cout == 128) ? 160 : 80;
                int ts = (Tin + span - 1) / span;
                dim3 g(25 * ts, 1, nc);
                if (c.cout == 64)
                    conv_mfma<1, 4, 80, 1, 1><<<g, 256, 0, stream>>>(bufs + HB, prep + mixoff[b], bufs + GB,
                        cinp[b], Tin, Tin, PER_N, 480000, PER_N, 960000);
                else if (c.cout == 128)
                    conv_mfma<2, 2, 80, 1, 1><<<g, 256, 0, stream>>>(bufs + HB, prep + mixoff[b], bufs + GB,
                        cinp[b], Tin, Tin, PER_N, 480000, PER_N, 960000);
                else
                    conv_mfma<4, 1, 80, 1, 1><<<g, 256, 0, stream>>>(bufs + HB, prep + mixoff[b], bufs + GB,
                        cinp[b], Tin, Tin, PER_N, 480000, PER_N, 960000);
            }
            // 3) temporal conv (TAPS=9) : g -> fA
            {
                if (b <= 3) {
                    conv_mfma<1, 4, 80, 9, 1><<<dim3(25, 1, nc), 256, 0, stream>>>(bufs + GB, prep + wtoff[b], bufs + FA,
                        c.cout, Tin, Tout, PER_N, 960000, PER_N, 480000);
                } else if (b == 4) {
                    conv_mfma<2, 2, 64, 9, 2><<<dim3(50, 1, nc), 256, 0, stream>>>(bufs + GB, prep + wtoff[b], bufs + FA,
                        c.cout, Tin, Tout, PER_N, 960000, PER_N, 480000);
                } else if (b <= 6) {
                    conv_mfma<2, 2, 80, 9, 1><<<dim3(25, 1, nc), 256, 0, stream>>>(bufs + GB, prep + wtoff[b], bufs + FA,
                        c.cout, Tin, Tout, PER_N, 960000, PER_N, 480000);
                } else if (b == 7) {
                    conv_mfma<4, 1, 80, 9, 2><<<dim3(25, 1, nc), 256, 0, stream>>>(bufs + GB, prep + wtoff[b], bufs + FA,
                        c.cout, Tin, Tout, PER_N, 960000, PER_N, 480000);
                } else {
                    conv_mfma<4, 1, 80, 9, 1><<<dim3(25, 1, nc), 256, 0, stream>>>(bufs + GB, prep + wtoff[b], bufs + FA,
                        c.cout, Tin, Tout, PER_N, 960000, PER_N, 480000);
                }
            }
        }
        // 4) final transpose to NCTV f32
        out_tr<<<dim3(75, nc), 256, 0, stream>>>(bufs + FA, out + (size_t)nb * 480000, PER_N, 480000);
    }
}

// Round 4
// 5716.010 us; speedup vs baseline: 3.3576x; 1.4101x over previous
//
#include <hip/hip_runtime.h>
#include <cstdint>

typedef unsigned short u16;
typedef unsigned int u32;
typedef __attribute__((ext_vector_type(8))) short short8v;
typedef __attribute__((ext_vector_type(4))) float float4v;

#define MFMA16 __builtin_amdgcn_mfma_f32_16x16x32_bf16

__device__ __forceinline__ u16 f2bf(float x) {
    union { float f; u32 u; } c; c.f = x;
    return (u16)((c.u + 0x7FFFu + ((c.u >> 16) & 1u)) >> 16);
}
__device__ __forceinline__ float bf2f(u16 h) {
    union { u32 u; float f; } c; c.u = ((u32)h) << 16;
    return c.f;
}

// ===================== weight prep (identical to round 3) =====================
// dst layout: [tap][ic][p][kg][M][8], value = split_p( W[m][ic*32+kg*8+j][tap] )
__global__ __launch_bounds__(256)
void prep_w(const float* __restrict__ W, u16* __restrict__ dst,
            int M, int cin, int nIC, int TAPS, int total)
{
    int e = blockIdx.x * 256 + threadIdx.x;
    if (e >= total) return;
    int tmp = e;
    int j = tmp & 7; tmp >>= 3;
    int m = tmp % M; tmp /= M;
    int kg = tmp & 3; tmp >>= 2;
    int p = tmp & 1; tmp >>= 1;
    int ic = tmp % nIC;
    int tap = tmp / nIC;
    int i = ic * 32 + kg * 8 + j;
    float val = (i < cin) ? W[((size_t)m * cin + i) * TAPS + tap] : 0.f;
    u16 h = f2bf(val);
    dst[e] = p ? f2bf(val - bf2f(h)) : h;
}

// ===================== adjacency: block 0 (from raw x) =====================
// x: [n][300][25][3] f32 -> F_0 planes [25][300][32] (c>=3 zero), hi/lo
__global__ __launch_bounds__(256)
void adj0(const float* __restrict__ x, const float* __restrict__ Am,
          u16* __restrict__ dstb, long dst_nstride, int dst_poff)
{
    __shared__ float A_s[25][26];
    for (int i2 = threadIdx.x; i2 < 625; i2 += 256) A_s[i2 / 25][i2 % 25] = Am[i2];
    __syncthreads();
    int t = blockIdx.x * 256 + threadIdx.x;
    int nl = blockIdx.y;
    if (t >= 300) return;
    const float* xp = x + ((size_t)nl * 300 + t) * 75;
    float acc[25][3];
#pragma unroll
    for (int w = 0; w < 25; ++w) { acc[w][0] = 0.f; acc[w][1] = 0.f; acc[w][2] = 0.f; }
    for (int v = 0; v < 25; ++v) {
        float x0 = xp[v * 3 + 0], x1 = xp[v * 3 + 1], x2 = xp[v * 3 + 2];
#pragma unroll
        for (int w = 0; w < 25; ++w) {
            float a = A_s[v][w];
            acc[w][0] = fmaf(a, x0, acc[w][0]);
            acc[w][1] = fmaf(a, x1, acc[w][1]);
            acc[w][2] = fmaf(a, x2, acc[w][2]);
        }
    }
    u16* dhi = dstb + (size_t)nl * dst_nstride;
    u16* dlo = dhi + dst_poff;
#pragma unroll
    for (int w = 0; w < 25; ++w) {
        u16 hb[32], lb[32];
#pragma unroll
        for (int c = 0; c < 32; ++c) { hb[c] = 0; lb[c] = 0; }
#pragma unroll
        for (int c = 0; c < 3; ++c) {
            float y = acc[w][c];
            u16 h = f2bf(y);
            hb[c] = h; lb[c] = f2bf(y - bf2f(h));
        }
        size_t o = ((size_t)w * 300 + t) * 32;
#pragma unroll
        for (int q = 0; q < 4; ++q) {
            *(uint4*)&dhi[o + q * 8] = *(const uint4*)&hb[q * 8];
            *(uint4*)&dlo[o + q * 8] = *(const uint4*)&lb[q * 8];
        }
    }
}

// ===================== adjacency: in-place on F =====================
// F[w][t][c] <- sum_v A[v][w] * F[v][t][c]; thread owns a (t,c4) column
// across all 25 v -> reads-then-writes disjoint columns: in-place safe.
__global__ __launch_bounds__(256)
void adj_ip(u16* fb, const float* __restrict__ Am, int C, int Tin,
            long nstride, int poff)
{
    __shared__ float A_s[25][26];
    for (int i2 = threadIdx.x; i2 < 625; i2 += 256) A_s[i2 / 25][i2 % 25] = Am[i2];
    __syncthreads();
    const int C4 = C >> 2;
    int idx = blockIdx.x * 256 + threadIdx.x;
    if (idx >= Tin * C4) return;
    int t = idx / C4;
    int c = (idx - t * C4) * 4;
    u16* hi = fb + (size_t)blockIdx.y * nstride;
    u16* lo = hi + poff;
    float a0[25], a1[25], a2[25], a3[25];
#pragma unroll
    for (int w = 0; w < 25; ++w) { a0[w] = 0.f; a1[w] = 0.f; a2[w] = 0.f; a3[w] = 0.f; }
    for (int v = 0; v < 25; ++v) {
        size_t o = (size_t)(v * Tin + t) * C + c;
        ushort4 h4 = *(const ushort4*)&hi[o];
        ushort4 l4 = *(const ushort4*)&lo[o];
        float y0 = bf2f(h4.x) + bf2f(l4.x);
        float y1 = bf2f(h4.y) + bf2f(l4.y);
        float y2 = bf2f(h4.z) + bf2f(l4.z);
        float y3 = bf2f(h4.w) + bf2f(l4.w);
#pragma unroll
        for (int w = 0; w < 25; ++w) {
            float a = A_s[v][w];
            a0[w] = fmaf(a, y0, a0[w]);
            a1[w] = fmaf(a, y1, a1[w]);
            a2[w] = fmaf(a, y2, a2[w]);
            a3[w] = fmaf(a, y3, a3[w]);
        }
    }
#pragma unroll
    for (int w = 0; w < 25; ++w) {
        size_t o = (size_t)(w * Tin + t) * C + c;
        ushort4 ho, lo4; u16 h;
        h = f2bf(a0[w]); ho.x = h; lo4.x = f2bf(a0[w] - bf2f(h));
        h = f2bf(a1[w]); ho.y = h; lo4.y = f2bf(a1[w] - bf2f(h));
        h = f2bf(a2[w]); ho.z = h; lo4.z = f2bf(a2[w] - bf2f(h));
        h = f2bf(a3[w]); ho.w = h; lo4.w = f2bf(a3[w] - bf2f(h));
        *(ushort4*)&hi[o] = ho;
        *(ushort4*)&lo[o] = lo4;
    }
}

// ===================== unified conv-GEMM via MFMA (split bf16) =====================
// dst[o][v][t'] = relu( sum_{i,k} W[o][i][k] * src[i][v][t'*S + k - PAD] )
// Block: 64-o tile x 4 v (one per wave) x NT t'-strip. B window per 32-ch
// K-chunk staged once, reused across all taps; A staged per tap-pair (16KB).
// OUTF32: final layer writes f32 NCTV directly into d_out.
template<int NT, int TAPS, int S, int OUTF32>
__global__ __launch_bounds__(256, 2)
void conv2(const u16* __restrict__ srcb, const u16* __restrict__ wtp,
           u16* __restrict__ dstb, float* __restrict__ outb,
           int K, int M, int Tin, int Tout,
           long src_nstride, int src_poff, long dst_nstride, int dst_poff,
           int o_tiles)
{
    constexpr int PADW = (TAPS == 1) ? 0 : 4;
    constexpr int WIN = NT * S + 2 * PADW;
    constexpr int BP = (S == 2) ? 44 : 40;      // 2-way-max bank pattern
    constexpr int NF = NT / 16;
    constexpr int ATAPS = (TAPS < 2) ? 1 : 2;
    constexpr int A_USH = ATAPS * 4096;         // [atap][2pl][4kg][64o][8]
    constexpr int B_USH = 4 * 2 * WIN * BP;
    constexpr int E_F32 = 4 * NT * 18;
    constexpr int SM1 = (A_USH + B_USH) * 2;
    constexpr int SM2 = A_USH * 2 + E_F32 * 4;
    constexpr int SMEM = SM1 > SM2 ? SM1 : SM2;
    __shared__ __align__(16) char smem[SMEM];
    u16* As = (u16*)smem;
    u16* Bs = (u16*)(smem + A_USH * 2);
    float* E = (float*)(smem + A_USH * 2);      // overlays B after main loop

    const int tid = threadIdx.x;
    const int l15 = tid & 15;
    const int lkg = (tid >> 4) & 3;
    const int wv = tid >> 6;

    const int ot = blockIdx.x % o_tiles;
    const int vg = blockIdx.x / o_tiles;        // 0..6
    const int strip = blockIdx.y;
    const int nl = blockIdx.z;
    const int t0 = strip * NT;
    const int wstart = t0 * S - PADW;
    const int v = vg * 4 + wv;

    const u16* shi = srcb + (size_t)nl * src_nstride;
    const u16* slo = shi + src_poff;

    float4v acc[4][NF];
#pragma unroll
    for (int mt = 0; mt < 4; ++mt)
#pragma unroll
        for (int nf = 0; nf < NF; ++nf) acc[mt][nf] = (float4v)0.f;

    const int nIC = K >> 5;
    for (int ic = 0; ic < nIC; ++ic) {
        __syncthreads();                         // prev B/A reads complete
        // ---- stage B windows (4 waves, both planes) ----
        {
            constexpr int W4 = WIN * 4;
            constexpr int BCH = 8 * W4;
            const int cbase = ic * 32;
            for (int q = tid; q < BCH; q += 256) {
                int w2 = q / (2 * W4);
                int rem = q - w2 * (2 * W4);
                int pl = rem / W4;
                int r2 = rem - pl * W4;
                int row = r2 >> 2, part = r2 & 3;
                int vv = vg * 4 + w2;
                int t = wstart + row;
                uint4 val = {0u, 0u, 0u, 0u};
                if (vv < 25 && t >= 0 && t < Tin)
                    val = *(const uint4*)((pl ? slo : shi) +
                          (size_t)(vv * Tin + t) * K + cbase + part * 8);
                *(uint4*)&Bs[((w2 * 2 + pl) * WIN + row) * BP + part * 8] = val;
            }
        }
        const int ntp = (TAPS + ATAPS - 1) / ATAPS;
        for (int tp = 0; tp < ntp; ++tp) {
            if (tp) __syncthreads();             // prev tap-pair A reads done
            // ---- stage A (tap pair), linear 16B copies from prep ----
            {
                int ntap = TAPS - tp * ATAPS; if (ntap > ATAPS) ntap = ATAPS;
                const int ACH = ntap * 512;
                for (int q = tid; q < ACH; q += 256) {
                    int ti = q >> 9;
                    int r = q & 511;
                    int tap = tp * ATAPS + ti;
                    int pl = r >> 8, r2 = r & 255, kg = r2 >> 6, o = r2 & 63;
                    const u16* src = wtp +
                        ((size_t)(((tap * nIC + ic) * 2 + pl) * 4 + kg) * M + ot * 64 + o) * 8;
                    *(uint4*)&As[q * 8] = *(const uint4*)src;
                }
            }
            __syncthreads();
            // ---- compute ----
            const int tlim = TAPS - tp * ATAPS;
#pragma unroll
            for (int ti = 0; ti < ATAPS; ++ti) {
                if (ti < tlim) {
                    const int tap = tp * ATAPS + ti;
                    short8v ah[4], al[4];
#pragma unroll
                    for (int mt = 0; mt < 4; ++mt) {
                        ah[mt] = *(const short8v*)&As[(((ti * 2 + 0) * 4 + lkg) * 64 + mt * 16 + l15) * 8];
                        al[mt] = *(const short8v*)&As[(((ti * 2 + 1) * 4 + lkg) * 64 + mt * 16 + l15) * 8];
                    }
#pragma unroll
                    for (int nf = 0; nf < NF; ++nf) {
                        const int row = (nf * 16 + l15) * S + tap;
                        const u16* bb = &Bs[((wv * 2) * WIN + row) * BP + lkg * 8];
                        short8v bh = *(const short8v*)bb;
                        short8v bl = *(const short8v*)(bb + WIN * BP);
#pragma unroll
                        for (int mt = 0; mt < 4; ++mt) {
                            acc[mt][nf] = MFMA16(ah[mt], bh, acc[mt][nf], 0, 0, 0);
                            acc[mt][nf] = MFMA16(ah[mt], bl, acc[mt][nf], 0, 0, 0);
                            acc[mt][nf] = MFMA16(al[mt], bh, acc[mt][nf], 0, 0, 0);
                        }
                    }
                }
            }
        }
    }

    // ---- epilogue: per 16-o group, LDS transpose, relu, store ----
    u16* dhi = dstb ? dstb + (size_t)nl * dst_nstride : nullptr;
    u16* dlo = dhi ? dhi + dst_poff : nullptr;
    float* outn = OUTF32 ? outb + (size_t)nl * 480000 : nullptr;
#pragma unroll
    for (int m = 0; m < 4; ++m) {
        __syncthreads();
        if (v < 25) {
#pragma unroll
            for (int nf = 0; nf < NF; ++nf)
#pragma unroll
                for (int r = 0; r < 4; ++r)
                    E[(wv * NT + nf * 16 + l15) * 18 + lkg * 4 + r] = acc[m][nf][r];
        }
        __syncthreads();
        if (!OUTF32) {
            for (int q = tid; q < 4 * NT; q += 256) {
                int cw = q / NT, t = q - cw * NT;
                int vv = vg * 4 + cw, tg = t0 + t;
                if (vv < 25 && tg < Tout) {
                    u16 hb[16], lb[16];
#pragma unroll
                    for (int j = 0; j < 16; ++j) {
                        float y = fmaxf(E[(cw * NT + t) * 18 + j], 0.f);
                        u16 h = f2bf(y); hb[j] = h; lb[j] = f2bf(y - bf2f(h));
                    }
                    size_t o = (size_t)(vv * Tout + tg) * M + ot * 64 + m * 16;
                    *(uint4*)&dhi[o] = *(const uint4*)&hb[0];
                    *(uint4*)&dhi[o + 8] = *(const uint4*)&hb[8];
                    *(uint4*)&dlo[o] = *(const uint4*)&lb[0];
                    *(uint4*)&dlo[o + 8] = *(const uint4*)&lb[8];
                }
            }
        } else {
            int v0 = vg * 4;
            int nv = 25 - v0; if (nv > 4) nv = 4;
            for (int q = tid; q < 16 * NT; q += 256) {
                int ol = q / NT, t = q - ol * NT;
                int tg = t0 + t;
                if (tg < Tout) {
                    int o = ot * 64 + m * 16 + ol;
                    float* op = outn + (size_t)o * 1875 + tg * 25 + v0;
                    for (int cw = 0; cw < nv; ++cw)
                        op[cw] = fmaxf(E[(cw * NT + t) * 18 + ol], 0.f);
                }
            }
        }
    }
}

// ===================== host =====================
extern "C" void kernel_launch(void* const* d_in, const int* in_sizes, int n_in,
                              void* d_out, int out_size, void* d_ws, size_t ws_size,
                              hipStream_t stream)
{
    const float* x = (const float*)d_in[0];
    const float* A = (const float*)d_in[1];
    const float* WS[10];
    const float* WT[10];
    for (int i = 0; i < 10; ++i) {
        WS[i] = (const float*)d_in[2 + 2 * i];
        WT[i] = (const float*)d_in[3 + 2 * i];
    }
    float* outF = (float*)d_out;

    static const int KM[10]  = {32, 64, 64, 64, 64, 128, 128, 128, 256, 256}; // F channels (padded)
    static const int MM[10]  = {64, 64, 64, 64, 128, 128, 128, 256, 256, 256};
    static const int TIN[10] = {300, 300, 300, 300, 300, 150, 150, 150, 75, 75};
    static const int SS[10]  = {1, 1, 1, 1, 2, 1, 1, 2, 1, 1};

    // ---- prep buffer layout ----
    size_t mixoff[10], wtoff[10], off = 0;
    for (int b = 0; b < 10; ++b) {
        mixoff[b] = off; off += (size_t)(KM[b] / 32) * 64 * MM[b];
        wtoff[b] = off;  off += (size_t)9 * (MM[b] / 32) * 64 * MM[b];
    }
    u16* prep = (u16*)d_ws;
    size_t prep_bytes = ((off * 2 + 255) / 256) * 256;
    u16* ws_s = (u16*)((char*)d_ws + prep_bytes);
    size_t ws_spill = (ws_size > prep_bytes) ? ws_size - prep_bytes : 0;

    for (int b = 0; b < 10; ++b) {
        int nICm = KM[b] / 32;
        int totm = nICm * 64 * MM[b];
        prep_w<<<(totm + 255) / 256, 256, 0, stream>>>(
            WS[b], prep + mixoff[b], MM[b], (b == 0 ? 3 : KM[b]), nICm, 1, totm);
        int nICt = MM[b] / 32;
        int tott = 9 * nICt * 64 * MM[b];
        prep_w<<<(tott + 255) / 256, 256, 0, stream>>>(
            WT[b], prep + wtoff[b], MM[b], MM[b], nICt, 9, tott);
    }

    const long F_STR = 960000;                  // u16 per n (hi+lo, 480000 elems)
    const long S_STR = 1920000;                 // u16 per n (hi+lo, 960000 elems)
    const size_t F_PN_B = 1920000;              // == f32 out bytes per n
    const size_t S_PN_B = 3840000;
    const size_t dout_b = (size_t)out_size * 4;

    int done = 0;
    while (done < 64) {
        size_t used = (size_t)done * F_PN_B;
        size_t dout_rem = dout_b - used;
        int NC = (int)((dout_rem + ws_spill) / (F_PN_B + S_PN_B));
        if (NC > 64 - done) NC = 64 - done;
        if (NC < 1) NC = 1;
        int k_s = 0;
        for (;; --NC) {
            long rem_after_F = (long)dout_rem - (long)NC * (long)F_PN_B;
            k_s = rem_after_F > 0 ? (int)(rem_after_F / (long)S_PN_B) : 0;
            if (k_s > NC) k_s = NC;
            if ((size_t)(NC - k_s) * S_PN_B <= ws_spill) break;
            if (NC <= 1) { NC = 1; k_s = 0; break; }
        }
        u16* Fz = (u16*)d_out + used / 2;                         // F zone == out region
        u16* Sd = (u16*)d_out + (used + (size_t)NC * F_PN_B) / 2; // s zone (dout part)

        for (int b = 0; b < 10; ++b) {
            const int K = KM[b], M = MM[b], Tin = TIN[b], S = SS[b];
            const int Tout = (S == 1) ? Tin : Tin / 2;
            const int fpoff = (b == 0) ? 240000 : 480000;
            const int spoff = 25 * Tin * M;
            const int o_tiles = M / 64;
            const int mstrips = (Tin + 79) / 80;
            const int cNT = (S == 1) ? 80 : 32;
            const int cstrips = (Tout + cNT - 1) / cNT;

            // 1) adjacency (commuted ahead of mix; exact, f32 VALU)
            if (b == 0)
                adj0<<<dim3(2, NC), 256, 0, stream>>>(
                    x + (size_t)done * 22500, A, Fz, F_STR, 240000);
            else {
                int thr = Tin * (K >> 2);
                adj_ip<<<dim3((thr + 255) / 256, NC), 256, 0, stream>>>(
                    Fz, A, K, Tin, F_STR, 480000);
            }
            // 2+3) mix then temporal, split-launched over the s-zone split
            for (int part = 0; part < 2; ++part) {
                int n0 = part ? k_s : 0;
                int cnt = part ? NC - k_s : k_s;
                if (cnt <= 0) continue;
                u16* sb = part ? ws_s : Sd;
                u16* fb = Fz + (size_t)n0 * F_STR;

                conv2<80, 1, 1, 0><<<dim3(o_tiles * 7, mstrips, cnt), 256, 0, stream>>>(
                    fb, prep + mixoff[b], sb, nullptr, K, M, Tin, Tin,
                    F_STR, fpoff, S_STR, spoff, o_tiles);

                if (b == 9)
                    conv2<80, 9, 1, 1><<<dim3(o_tiles * 7, cstrips, cnt), 256, 0, stream>>>(
                        sb, prep + wtoff[b], nullptr,
                        outF + (size_t)(done + n0) * 480000,
                        M, M, Tin, Tout, S_STR, spoff, 0, 0, o_tiles);
                else if (S == 1)
                    conv2<80, 9, 1, 0><<<dim3(o_tiles * 7, cstrips, cnt), 256, 0, stream>>>(
                        sb, prep + wtoff[b], fb, nullptr, M, M, Tin, Tout,
                        S_STR, spoff, F_STR, 480000, o_tiles);
                else
                    conv2<32, 9, 2, 0><<<dim3(o_tiles * 7, cstrips, cnt), 256, 0, stream>>>(
                        sb, prep + wtoff[b], fb, nullptr, M, M, Tin, Tout,
                        S_STR, spoff, F_STR, 480000, o_tiles);
            }
        }
        done += NC;
    }
}

// Round 5
// 5313.827 us; speedup vs baseline: 3.6117x; 1.0757x over previous
//
#include <hip/hip_runtime.h>
#include <cstdint>

typedef unsigned short u16;
typedef unsigned int u32;
typedef __attribute__((ext_vector_type(8))) short short8v;
typedef __attribute__((ext_vector_type(4))) float float4v;

#define MFMA16 __builtin_amdgcn_mfma_f32_16x16x32_bf16

__device__ __forceinline__ u16 f2bf(float x) {
    union { float f; u32 u; } c; c.f = x;
    return (u16)((c.u + 0x7FFFu + ((c.u >> 16) & 1u)) >> 16);
}
__device__ __forceinline__ float bf2f(u16 h) {
    union { u32 u; float f; } c; c.u = ((u32)h) << 16;
    return c.f;
}

// ===================== weight prep =====================
// dst layout: [tap][ic][p][kg][M][8], value = split_p( W[m][ic*32+kg*8+j][tap] )
__global__ __launch_bounds__(256)
void prep_w(const float* __restrict__ W, u16* __restrict__ dst,
            int M, int cin, int nIC, int TAPS, int total)
{
    int e = blockIdx.x * 256 + threadIdx.x;
    if (e >= total) return;
    int tmp = e;
    int j = tmp & 7; tmp >>= 3;
    int m = tmp % M; tmp /= M;
    int kg = tmp & 3; tmp >>= 2;
    int p = tmp & 1; tmp >>= 1;
    int ic = tmp % nIC;
    int tap = tmp / nIC;
    int i = ic * 32 + kg * 8 + j;
    float val = (i < cin) ? W[((size_t)m * cin + i) * TAPS + tap] : 0.f;
    u16 h = f2bf(val);
    dst[e] = p ? f2bf(val - bf2f(h)) : h;
}

// ===================== adjacency: block 0 (from raw x) =====================
__global__ __launch_bounds__(256)
void adj0(const float* __restrict__ x, const float* __restrict__ Am,
          u16* __restrict__ dstb, long dst_nstride, int dst_poff)
{
    __shared__ float A_s[25][26];
    for (int i2 = threadIdx.x; i2 < 625; i2 += 256) A_s[i2 / 25][i2 % 25] = Am[i2];
    __syncthreads();
    int t = blockIdx.x * 256 + threadIdx.x;
    int nl = blockIdx.y;
    if (t >= 300) return;
    const float* xp = x + ((size_t)nl * 300 + t) * 75;
    float acc[25][3];
#pragma unroll
    for (int w = 0; w < 25; ++w) { acc[w][0] = 0.f; acc[w][1] = 0.f; acc[w][2] = 0.f; }
    for (int v = 0; v < 25; ++v) {
        float x0 = xp[v * 3 + 0], x1 = xp[v * 3 + 1], x2 = xp[v * 3 + 2];
#pragma unroll
        for (int w = 0; w < 25; ++w) {
            float a = A_s[v][w];
            acc[w][0] = fmaf(a, x0, acc[w][0]);
            acc[w][1] = fmaf(a, x1, acc[w][1]);
            acc[w][2] = fmaf(a, x2, acc[w][2]);
        }
    }
    u16* dhi = dstb + (size_t)nl * dst_nstride;
    u16* dlo = dhi + dst_poff;
#pragma unroll
    for (int w = 0; w < 25; ++w) {
        u16 hb[32], lb[32];
#pragma unroll
        for (int c = 0; c < 32; ++c) { hb[c] = 0; lb[c] = 0; }
#pragma unroll
        for (int c = 0; c < 3; ++c) {
            float y = acc[w][c];
            u16 h = f2bf(y);
            hb[c] = h; lb[c] = f2bf(y - bf2f(h));
        }
        size_t o = ((size_t)w * 300 + t) * 32;
#pragma unroll
        for (int q = 0; q < 4; ++q) {
            *(uint4*)&dhi[o + q * 8] = *(const uint4*)&hb[q * 8];
            *(uint4*)&dlo[o + q * 8] = *(const uint4*)&lb[q * 8];
        }
    }
}

// ===================== adjacency: in-place on F =====================
__global__ __launch_bounds__(256)
void adj_ip(u16* fb, const float* __restrict__ Am, int C, int Tin,
            long nstride, int poff)
{
    __shared__ float A_s[25][26];
    for (int i2 = threadIdx.x; i2 < 625; i2 += 256) A_s[i2 / 25][i2 % 25] = Am[i2];
    __syncthreads();
    const int C4 = C >> 2;
    int idx = blockIdx.x * 256 + threadIdx.x;
    if (idx >= Tin * C4) return;
    int t = idx / C4;
    int c = (idx - t * C4) * 4;
    u16* hi = fb + (size_t)blockIdx.y * nstride;
    u16* lo = hi + poff;
    float a0[25], a1[25], a2[25], a3[25];
#pragma unroll
    for (int w = 0; w < 25; ++w) { a0[w] = 0.f; a1[w] = 0.f; a2[w] = 0.f; a3[w] = 0.f; }
    for (int v = 0; v < 25; ++v) {
        size_t o = (size_t)(v * Tin + t) * C + c;
        ushort4 h4 = *(const ushort4*)&hi[o];
        ushort4 l4 = *(const ushort4*)&lo[o];
        float y0 = bf2f(h4.x) + bf2f(l4.x);
        float y1 = bf2f(h4.y) + bf2f(l4.y);
        float y2 = bf2f(h4.z) + bf2f(l4.z);
        float y3 = bf2f(h4.w) + bf2f(l4.w);
#pragma unroll
        for (int w = 0; w < 25; ++w) {
            float a = A_s[v][w];
            a0[w] = fmaf(a, y0, a0[w]);
            a1[w] = fmaf(a, y1, a1[w]);
            a2[w] = fmaf(a, y2, a2[w]);
            a3[w] = fmaf(a, y3, a3[w]);
        }
    }
#pragma unroll
    for (int w = 0; w < 25; ++w) {
        size_t o = (size_t)(w * Tin + t) * C + c;
        ushort4 ho, lo4; u16 h;
        h = f2bf(a0[w]); ho.x = h; lo4.x = f2bf(a0[w] - bf2f(h));
        h = f2bf(a1[w]); ho.y = h; lo4.y = f2bf(a1[w] - bf2f(h));
        h = f2bf(a2[w]); ho.z = h; lo4.z = f2bf(a2[w] - bf2f(h));
        h = f2bf(a3[w]); ho.w = h; lo4.w = f2bf(a3[w] - bf2f(h));
        *(ushort4*)&hi[o] = ho;
        *(ushort4*)&lo[o] = lo4;
    }
}

// ===================== conv-GEMM via MFMA (split bf16), pipelined =====================
// A (weights) global->regs (double-banked, prefetched 1 tap ahead; L2-broadcast).
// B (acts) in LDS, staged per 32-ch K-chunk via reg-prefetch across the ic loop.
// 2 barriers per K-chunk. XCD-chunked bijective work mapping, n fastest, ot slowest.
template<int NT, int TAPS, int S, int OUTF32>
__global__ __launch_bounds__(256, 2)
void conv3(const u16* __restrict__ srcb, const u16* __restrict__ wtp,
           u16* __restrict__ dstb, float* __restrict__ outb,
           int K, int M, int Tin, int Tout,
           long src_nstride, int src_poff, long dst_nstride, int dst_poff,
           int o_tiles, int strips, int cnt)
{
    constexpr int PADW = (TAPS == 1) ? 0 : 4;
    constexpr int WIN = NT * S + 2 * PADW;
    constexpr int BP = 40;                    // proven conflict-free pitch
    constexpr int NF = NT / 16;
    constexpr int NB = WIN / 8;               // B chunks per thread
    constexpr int B_BYTES = 4 * 2 * WIN * BP * 2;
    constexpr int E_BYTES = 4 * NT * 18 * 4;
    constexpr int SMEM = B_BYTES > E_BYTES ? B_BYTES : E_BYTES;
    __shared__ __align__(16) char smem[SMEM];
    u16* Bs = (u16*)smem;
    float* E = (float*)smem;

    const int tid = threadIdx.x;
    const int l15 = tid & 15;
    const int lkg = (tid >> 4) & 3;
    const int wv = tid >> 6;

    // ---- bijective XCD-chunked work id (m204) ----
    int W;
    {
        const int nwg = gridDim.x;
        int q = nwg >> 3, r = nwg & 7;
        int xcd = blockIdx.x & 7, idx = blockIdx.x >> 3;
        W = (xcd < r ? xcd * (q + 1) : r * (q + 1) + (xcd - r) * q) + idx;
    }
    const int nl = W % cnt; int r1 = W / cnt;
    const int strip = r1 % strips; r1 /= strips;
    const int vg = r1 % 7;
    const int ot = r1 / 7;

    const int t0 = strip * NT;
    const int wstart = t0 * S - PADW;
    const int v = vg * 4 + wv;
    const int nIC = K >> 5;
    const int obase = ot * 64 + l15;

    const u16* shi = srcb + (size_t)nl * src_nstride;
    const u16* slo = shi + src_poff;

    float4v acc[4][NF];
#pragma unroll
    for (int mt = 0; mt < 4; ++mt)
#pragma unroll
        for (int nf = 0; nf < NF; ++nf) acc[mt][nf] = (float4v)0.f;

    // ---- precompute B staging offsets (ic-invariant) ----
    int bofs[NB], goff[NB];
#pragma unroll
    for (int j = 0; j < NB; ++j) {
        constexpr int W4 = WIN * 4;
        int q = j * 256 + tid;
        int w2 = q / (2 * W4);
        int rem = q - w2 * 2 * W4;
        int pl = rem / W4;
        int r2 = rem - pl * W4;
        int row = r2 >> 2, part = r2 & 3;
        int vv = vg * 4 + w2;
        int t = wstart + row;
        bofs[j] = ((w2 * 2 + pl) * WIN + row) * BP + part * 8;
        bool ok = (vv < 25) && (t >= 0) && (t < Tin);
        goff[j] = ok ? (int)(((vv * Tin + t) * K) + part * 8) | (pl << 30) : -1;
    }

    uint4 areg0[8], areg1[8], breg[NB];

    auto prefA = [&](uint4 (&a)[8], int tap, int icc) {
#pragma unroll
        for (int pl = 0; pl < 2; ++pl)
#pragma unroll
            for (int mt = 0; mt < 4; ++mt)
                a[pl * 4 + mt] = *(const uint4*)(wtp +
                    ((((size_t)(tap * nIC + icc) * 2 + pl) * 4 + lkg) * M + obase + mt * 16) * 8);
    };
    auto ctap = [&](const uint4 (&a)[8], int t) {
#pragma unroll
        for (int nf = 0; nf < NF; ++nf) {
            const int row = (nf * 16 + l15) * S + t;
            const u16* bb = &Bs[(wv * 2 * WIN + row) * BP + lkg * 8];
            short8v bh = *(const short8v*)bb;
            short8v bl = *(const short8v*)(bb + WIN * BP);
#pragma unroll
            for (int mt = 0; mt < 4; ++mt) {
                short8v ah = __builtin_bit_cast(short8v, a[mt]);
                short8v al = __builtin_bit_cast(short8v, a[4 + mt]);
                acc[mt][nf] = MFMA16(ah, bh, acc[mt][nf], 0, 0, 0);
                acc[mt][nf] = MFMA16(ah, bl, acc[mt][nf], 0, 0, 0);
                acc[mt][nf] = MFMA16(al, bh, acc[mt][nf], 0, 0, 0);
            }
        }
    };

    // ---- prologue prefetch ----
#pragma unroll
    for (int j = 0; j < NB; ++j) {
        uint4 val = {0u, 0u, 0u, 0u};
        if (goff[j] >= 0)
            val = *(const uint4*)(((goff[j] & 0x40000000) ? slo : shi) + (goff[j] & 0x3FFFFFFF));
        breg[j] = val;
    }
    prefA(areg0, 0, 0);

#pragma unroll 1
    for (int ic = 0; ic < nIC; ++ic) {
        const int icn = (ic + 1 < nIC) ? ic + 1 : ic;
        __syncthreads();                       // all reads of prev B done
#pragma unroll
        for (int j = 0; j < NB; ++j) *(uint4*)&Bs[bofs[j]] = breg[j];
        __syncthreads();                       // B visible
        // issue next-chunk B loads (land during the 9-tap compute)
#pragma unroll
        for (int j = 0; j < NB; ++j) {
            uint4 val = {0u, 0u, 0u, 0u};
            if (goff[j] >= 0)
                val = *(const uint4*)(((goff[j] & 0x40000000) ? slo : shi) +
                                      (goff[j] & 0x3FFFFFFF) + icn * 32);
            breg[j] = val;
        }
#pragma unroll
        for (int t = 0; t < TAPS; ++t) {
            const int tn = (t + 1 < TAPS) ? t + 1 : 0;
            const int icc = (t + 1 < TAPS) ? ic : icn;
            if ((t & 1) == 0) { prefA(areg1, tn, icc); ctap(areg0, t); }
            else              { prefA(areg0, tn, icc); ctap(areg1, t); }
        }
        if (TAPS & 1) {
#pragma unroll
            for (int j = 0; j < 8; ++j) areg0[j] = areg1[j];
        }
    }

    // ---- epilogue: per 16-o group, LDS transpose (E overlays Bs), relu, store ----
    u16* dhi = dstb ? dstb + (size_t)nl * dst_nstride : nullptr;
    u16* dlo = dhi ? dhi + dst_poff : nullptr;
    float* outn = OUTF32 ? outb + (size_t)nl * 480000 : nullptr;
#pragma unroll
    for (int m = 0; m < 4; ++m) {
        __syncthreads();
        if (v < 25) {
#pragma unroll
            for (int nf = 0; nf < NF; ++nf)
#pragma unroll
                for (int r = 0; r < 4; ++r)
                    E[(wv * NT + nf * 16 + l15) * 18 + lkg * 4 + r] = acc[m][nf][r];
        }
        __syncthreads();
        if (!OUTF32) {
            for (int q = tid; q < 4 * NT; q += 256) {
                int cw = q / NT, t = q - cw * NT;
                int vv = vg * 4 + cw, tg = t0 + t;
                if (vv < 25 && tg < Tout) {
                    u16 hb[16], lb[16];
#pragma unroll
                    for (int j = 0; j < 16; ++j) {
                        float y = fmaxf(E[(cw * NT + t) * 18 + j], 0.f);
                        u16 h = f2bf(y); hb[j] = h; lb[j] = f2bf(y - bf2f(h));
                    }
                    size_t o = (size_t)(vv * Tout + tg) * M + ot * 64 + m * 16;
                    *(uint4*)&dhi[o] = *(const uint4*)&hb[0];
                    *(uint4*)&dhi[o + 8] = *(const uint4*)&hb[8];
                    *(uint4*)&dlo[o] = *(const uint4*)&lb[0];
                    *(uint4*)&dlo[o + 8] = *(const uint4*)&lb[8];
                }
            }
        } else {
            int v0 = vg * 4;
            int nv = 25 - v0; if (nv > 4) nv = 4;
            for (int q = tid; q < 16 * NT; q += 256) {
                int ol = q / NT, t = q - ol * NT;
                int tg = t0 + t;
                if (tg < Tout) {
                    int o = ot * 64 + m * 16 + ol;
                    float* op = outn + (size_t)o * 1875 + tg * 25 + v0;
                    for (int cw = 0; cw < nv; ++cw)
                        op[cw] = fmaxf(E[(cw * NT + t) * 18 + ol], 0.f);
                }
            }
        }
    }
}

// ===================== host =====================
extern "C" void kernel_launch(void* const* d_in, const int* in_sizes, int n_in,
                              void* d_out, int out_size, void* d_ws, size_t ws_size,
                              hipStream_t stream)
{
    const float* x = (const float*)d_in[0];
    const float* A = (const float*)d_in[1];
    const float* WS[10];
    const float* WT[10];
    for (int i = 0; i < 10; ++i) {
        WS[i] = (const float*)d_in[2 + 2 * i];
        WT[i] = (const float*)d_in[3 + 2 * i];
    }
    float* outF = (float*)d_out;

    static const int KM[10]  = {32, 64, 64, 64, 64, 128, 128, 128, 256, 256};
    static const int MM[10]  = {64, 64, 64, 64, 128, 128, 128, 256, 256, 256};
    static const int TIN[10] = {300, 300, 300, 300, 300, 150, 150, 150, 75, 75};
    static const int SS[10]  = {1, 1, 1, 1, 2, 1, 1, 2, 1, 1};

    size_t mixoff[10], wtoff[10], off = 0;
    for (int b = 0; b < 10; ++b) {
        mixoff[b] = off; off += (size_t)(KM[b] / 32) * 64 * MM[b];
        wtoff[b] = off;  off += (size_t)9 * (MM[b] / 32) * 64 * MM[b];
    }
    u16* prep = (u16*)d_ws;
    size_t prep_bytes = ((off * 2 + 255) / 256) * 256;
    u16* ws_s = (u16*)((char*)d_ws + prep_bytes);
    size_t ws_spill = (ws_size > prep_bytes) ? ws_size - prep_bytes : 0;

    for (int b = 0; b < 10; ++b) {
        int nICm = KM[b] / 32;
        int totm = nICm * 64 * MM[b];
        prep_w<<<(totm + 255) / 256, 256, 0, stream>>>(
            WS[b], prep + mixoff[b], MM[b], (b == 0 ? 3 : KM[b]), nICm, 1, totm);
        int nICt = MM[b] / 32;
        int tott = 9 * nICt * 64 * MM[b];
        prep_w<<<(tott + 255) / 256, 256, 0, stream>>>(
            WT[b], prep + wtoff[b], MM[b], MM[b], nICt, 9, tott);
    }

    const long F_STR = 960000;
    const long S_STR = 1920000;
    const size_t F_PN_B = 1920000;
    const size_t S_PN_B = 3840000;
    const size_t dout_b = (size_t)out_size * 4;

    int done = 0;
    while (done < 64) {
        size_t used = (size_t)done * F_PN_B;
        size_t dout_rem = dout_b - used;
        int NC = (int)((dout_rem + ws_spill) / (F_PN_B + S_PN_B));
        if (NC > 64 - done) NC = 64 - done;
        if (NC < 1) NC = 1;
        int k_s = 0;
        for (;; --NC) {
            long rem_after_F = (long)dout_rem - (long)NC * (long)F_PN_B;
            k_s = rem_after_F > 0 ? (int)(rem_after_F / (long)S_PN_B) : 0;
            if (k_s > NC) k_s = NC;
            if ((size_t)(NC - k_s) * S_PN_B <= ws_spill) break;
            if (NC <= 1) { NC = 1; k_s = 0; break; }
        }
        u16* Fz = (u16*)d_out + used / 2;
        u16* Sd = (u16*)d_out + (used + (size_t)NC * F_PN_B) / 2;

        for (int b = 0; b < 10; ++b) {
            const int K = KM[b], M = MM[b], Tin = TIN[b], S = SS[b];
            const int Tout = (S == 1) ? Tin : Tin / 2;
            const int fpoff = (b == 0) ? 240000 : 480000;
            const int spoff = 25 * Tin * M;
            const int o_tiles = M / 64;
            const int mstrips = (Tin + 79) / 80;
            const int cNT = (S == 1) ? 80 : 32;
            const int cstrips = (Tout + cNT - 1) / cNT;

            if (b == 0)
                adj0<<<dim3(2, NC), 256, 0, stream>>>(
                    x + (size_t)done * 22500, A, Fz, F_STR, 240000);
            else {
                int thr = Tin * (K >> 2);
                adj_ip<<<dim3((thr + 255) / 256, NC), 256, 0, stream>>>(
                    Fz, A, K, Tin, F_STR, 480000);
            }

            for (int part = 0; part < 2; ++part) {
                int n0 = part ? k_s : 0;
                int cnt = part ? NC - k_s : k_s;
                if (cnt <= 0) continue;
                u16* sb = part ? ws_s : Sd;
                u16* fb = Fz + (size_t)n0 * F_STR;

                conv3<80, 1, 1, 0><<<dim3(o_tiles * 7 * mstrips * cnt), 256, 0, stream>>>(
                    fb, prep + mixoff[b], sb, nullptr, K, M, Tin, Tin,
                    F_STR, fpoff, S_STR, spoff, o_tiles, mstrips, cnt);

                if (b == 9)
                    conv3<80, 9, 1, 1><<<dim3(o_tiles * 7 * cstrips * cnt), 256, 0, stream>>>(
                        sb, prep + wtoff[b], nullptr,
                        outF + (size_t)(done + n0) * 480000,
                        M, M, Tin, Tout, S_STR, spoff, 0, 0, o_tiles, cstrips, cnt);
                else if (S == 1)
                    conv3<80, 9, 1, 0><<<dim3(o_tiles * 7 * cstrips * cnt), 256, 0, stream>>>(
                        sb, prep + wtoff[b], fb, nullptr, M, M, Tin, Tout,
                        S_STR, spoff, F_STR, 480000, o_tiles, cstrips, cnt);
                else
                    conv3<32, 9, 2, 0><<<dim3(o_tiles * 7 * cstrips * cnt), 256, 0, stream>>>(
                        sb, prep + wtoff[b], fb, nullptr, M, M, Tin, Tout,
                        S_STR, spoff, F_STR, 480000, o_tiles, cstrips, cnt);
            }
        }
        done += NC;
    }
}

// Round 6
// 4095.206 us; speedup vs baseline: 4.6864x; 1.2976x over previous
//
#include <hip/hip_runtime.h>
#include <cstdint>

typedef unsigned short u16;
typedef unsigned int u32;
typedef __attribute__((ext_vector_type(8))) short short8v;
typedef __attribute__((ext_vector_type(4))) float float4v;

#define MFMA16 __builtin_amdgcn_mfma_f32_16x16x32_bf16

__device__ __forceinline__ u16 f2bf(float x) {
    union { float f; u32 u; } c; c.f = x;
    return (u16)((c.u + 0x7FFFu + ((c.u >> 16) & 1u)) >> 16);
}
__device__ __forceinline__ float bf2f(u16 h) {
    union { u32 u; float f; } c; c.u = ((u32)h) << 16;
    return c.f;
}

// global -> LDS direct DMA, 16B per lane. dest must be wave-uniform base.
__device__ __forceinline__ void dma16(const void* g, void* l) {
    __builtin_amdgcn_global_load_lds(
        (const __attribute__((address_space(1))) u32*)g,
        (__attribute__((address_space(3))) u32*)l, 16, 0, 0);
}

// ===================== zero page init =====================
__global__ void zinit(u32* p) { p[threadIdx.x] = 0u; }   // 256 thr -> 1024 B

// ===================== weight prep =====================
// dst layout: [tap][ic][p][kg][M][8], value = split_p( W[m][ic*32+kg*8+j][tap] )
__global__ __launch_bounds__(256)
void prep_w(const float* __restrict__ W, u16* __restrict__ dst,
            int M, int cin, int nIC, int TAPS, int total)
{
    int e = blockIdx.x * 256 + threadIdx.x;
    if (e >= total) return;
    int tmp = e;
    int j = tmp & 7; tmp >>= 3;
    int m = tmp % M; tmp /= M;
    int kg = tmp & 3; tmp >>= 2;
    int p = tmp & 1; tmp >>= 1;
    int ic = tmp % nIC;
    int tap = tmp / nIC;
    int i = ic * 32 + kg * 8 + j;
    float val = (i < cin) ? W[((size_t)m * cin + i) * TAPS + tap] : 0.f;
    u16 h = f2bf(val);
    dst[e] = p ? f2bf(val - bf2f(h)) : h;
}

// ===================== adjacency: block 0 (from raw x) =====================
__global__ __launch_bounds__(256)
void adj0(const float* __restrict__ x, const float* __restrict__ Am,
          u16* __restrict__ dstb, long dst_nstride, int dst_poff)
{
    __shared__ float A_s[25][26];
    for (int i2 = threadIdx.x; i2 < 625; i2 += 256) A_s[i2 / 25][i2 % 25] = Am[i2];
    __syncthreads();
    int t = blockIdx.x * 256 + threadIdx.x;
    int nl = blockIdx.y;
    if (t >= 300) return;
    const float* xp = x + ((size_t)nl * 300 + t) * 75;
    float acc[25][3];
#pragma unroll
    for (int w = 0; w < 25; ++w) { acc[w][0] = 0.f; acc[w][1] = 0.f; acc[w][2] = 0.f; }
    for (int v = 0; v < 25; ++v) {
        float x0 = xp[v * 3 + 0], x1 = xp[v * 3 + 1], x2 = xp[v * 3 + 2];
#pragma unroll
        for (int w = 0; w < 25; ++w) {
            float a = A_s[v][w];
            acc[w][0] = fmaf(a, x0, acc[w][0]);
            acc[w][1] = fmaf(a, x1, acc[w][1]);
            acc[w][2] = fmaf(a, x2, acc[w][2]);
        }
    }
    u16* dhi = dstb + (size_t)nl * dst_nstride;
    u16* dlo = dhi + dst_poff;
#pragma unroll
    for (int w = 0; w < 25; ++w) {
        u16 hb[32], lb[32];
#pragma unroll
        for (int c = 0; c < 32; ++c) { hb[c] = 0; lb[c] = 0; }
#pragma unroll
        for (int c = 0; c < 3; ++c) {
            float y = acc[w][c];
            u16 h = f2bf(y);
            hb[c] = h; lb[c] = f2bf(y - bf2f(h));
        }
        size_t o = ((size_t)w * 300 + t) * 32;
#pragma unroll
        for (int q = 0; q < 4; ++q) {
            *(uint4*)&dhi[o + q * 8] = *(const uint4*)&hb[q * 8];
            *(uint4*)&dlo[o + q * 8] = *(const uint4*)&lb[q * 8];
        }
    }
}

// ===================== adjacency: in-place on F =====================
__global__ __launch_bounds__(256)
void adj_ip(u16* fb, const float* __restrict__ Am, int C, int Tin,
            long nstride, int poff)
{
    __shared__ float A_s[25][26];
    for (int i2 = threadIdx.x; i2 < 625; i2 += 256) A_s[i2 / 25][i2 % 25] = Am[i2];
    __syncthreads();
    const int C4 = C >> 2;
    int idx = blockIdx.x * 256 + threadIdx.x;
    if (idx >= Tin * C4) return;
    int t = idx / C4;
    int c = (idx - t * C4) * 4;
    u16* hi = fb + (size_t)blockIdx.y * nstride;
    u16* lo = hi + poff;
    float a0[25], a1[25], a2[25], a3[25];
#pragma unroll
    for (int w = 0; w < 25; ++w) { a0[w] = 0.f; a1[w] = 0.f; a2[w] = 0.f; a3[w] = 0.f; }
    for (int v = 0; v < 25; ++v) {
        size_t o = (size_t)(v * Tin + t) * C + c;
        ushort4 h4 = *(const ushort4*)&hi[o];
        ushort4 l4 = *(const ushort4*)&lo[o];
        float y0 = bf2f(h4.x) + bf2f(l4.x);
        float y1 = bf2f(h4.y) + bf2f(l4.y);
        float y2 = bf2f(h4.z) + bf2f(l4.z);
        float y3 = bf2f(h4.w) + bf2f(l4.w);
#pragma unroll
        for (int w = 0; w < 25; ++w) {
            float a = A_s[v][w];
            a0[w] = fmaf(a, y0, a0[w]);
            a1[w] = fmaf(a, y1, a1[w]);
            a2[w] = fmaf(a, y2, a2[w]);
            a3[w] = fmaf(a, y3, a3[w]);
        }
    }
#pragma unroll
    for (int w = 0; w < 25; ++w) {
        size_t o = (size_t)(w * Tin + t) * C + c;
        ushort4 ho, lo4; u16 h;
        h = f2bf(a0[w]); ho.x = h; lo4.x = f2bf(a0[w] - bf2f(h));
        h = f2bf(a1[w]); ho.y = h; lo4.y = f2bf(a1[w] - bf2f(h));
        h = f2bf(a2[w]); ho.z = h; lo4.z = f2bf(a2[w] - bf2f(h));
        h = f2bf(a3[w]); ho.w = h; lo4.w = f2bf(a3[w] - bf2f(h));
        *(ushort4*)&hi[o] = ho;
        *(ushort4*)&lo[o] = lo4;
    }
}

// ===================== conv-GEMM via MFMA (split bf16), DMA-staged =====================
// dst[o][v][t'] = relu( sum_{i,k} W[o][i][k] * src[i][v][t'*S + k - PAD] )
// B: global_load_lds double-buffer, sigma part-swizzle (source+read), zero-page halo.
// A: global->reg, 3 banks, distance-2 prefetch (9%3==0 -> static t%3 banks).
// S==2 windows phase-split so fragment reads step 1 LDS row (2-way banks).
template<int VW, int NT, int TAPS, int S, int OUTF32>
__global__ __launch_bounds__(256, 2)
void conv4(const u16* __restrict__ srcb, const u16* __restrict__ wtp,
           u16* __restrict__ dstb, float* __restrict__ outb,
           int K, int M, int Tin, int Tout,
           long src_nstride, int src_poff, long dst_nstride, int dst_poff,
           int o_tiles, int strips, int cnt, const u16* __restrict__ zpage)
{
    constexpr int PADW = (TAPS == 1) ? 0 : 4;
    constexpr int NPH = (S == 2) ? 2 : 1;
    constexpr int RAW = (TAPS == 1) ? NT : ((S == 1) ? NT + 8 : NT + 4);
    constexpr int RQ = 32 / (VW * NPH);
    constexpr int R = ((RAW + RQ - 1) / RQ) * RQ;       // rows per phase (padded)
    constexpr int NF = NT / 16;
    constexpr int NB = (VW * 2 * NPH * R * 4) / 256;    // 16B chunks per thread
    static_assert((VW * 2 * NPH * R * 4) % 256 == 0, "chunk mult");
    constexpr int BUF_U16 = VW * 2 * NPH * R * 32;
    constexpr int PL_STRIDE = NPH * R * 32;             // u16 between planes
    constexpr int EP = (VW == 2) ? 34 : 18;
    constexpr int SMEM_B = 2 * BUF_U16 * 2;
    static_assert(VW * NT * EP * 4 <= SMEM_B, "E fits");
    static_assert(SMEM_B <= 65536, "LDS limit");
    __shared__ __align__(16) char smem[SMEM_B];
    u16* Bs = (u16*)smem;
    float* E = (float*)smem;

    const int tid = threadIdx.x;
    const int l15 = tid & 15;
    const int lkg = (tid >> 4) & 3;
    const int wv = tid >> 6;
    const int vh = (VW == 2) ? (wv >> 1) : wv;
    const int oh = (VW == 2) ? (wv & 1) : 0;

    // ---- bijective XCD-chunked work id; ot fastest, nl, strip, vg slowest ----
    int Wk;
    {
        const int nwg = gridDim.x;
        int q8 = nwg >> 3, r8 = nwg & 7;
        int xcd = blockIdx.x & 7, bl = blockIdx.x >> 3;
        Wk = (xcd < r8 ? xcd * (q8 + 1) : r8 * (q8 + 1) + (xcd - r8) * q8) + bl;
    }
    const int ot = Wk % o_tiles; int r0 = Wk / o_tiles;
    const int nl = r0 % cnt; r0 /= cnt;
    const int strip = r0 % strips;
    const int vg = r0 / strips;

    const int t0 = strip * NT;
    const int wstart = t0 * S - PADW;
    const int nIC = K >> 5;
    const int obase = (VW == 2) ? (ot * 128 + oh * 64 + l15) : (ot * 64 + l15);

    const u16* shi = srcb + (size_t)nl * src_nstride;
    const u16* slo = shi + src_poff;
    const u16* pln[2] = { shi, slo };

    float4v acc[4][NF];
#pragma unroll
    for (int mt = 0; mt < 4; ++mt)
#pragma unroll
        for (int nf = 0; nf < NF; ++nf) acc[mt][nf] = (float4v)0.f;

    // ---- per-chunk B source pointers (ic-invariant; +ic*64 bytes per chunk) ----
    const char* bptr[NB];
#pragma unroll
    for (int k = 0; k < NB; ++k) {
        int d = k * 256 + tid;
        int part = d & 3; int d2 = d >> 2;
        int rw = d2 % R; d2 /= R;
        int ph = (NPH == 2) ? (d2 % NPH) : 0; d2 /= NPH;
        int pl = d2 & 1; int w2 = d2 >> 1;
        int v = vg * VW + w2;
        int t = (S == 2) ? (wstart + 2 * rw + ph) : (wstart + rw);
        int psrc = (part - (rw >> 1)) & 3;
        bool ok = (v < 25) && (t >= 0) && (t < Tin);
        bptr[k] = ok ? (const char*)(pln[pl] + ((size_t)(v * Tin + t) * K + psrc * 8))
                     : (const char*)zpage;
    }

    uint4 ar[3][8];

    auto stage = [&](int buf, int ic) {
        u16* base = Bs + buf * BUF_U16 + (tid & 192) * 8;  // wave-uniform lane-0 dest
#pragma unroll
        for (int k = 0; k < NB; ++k)
            dma16(bptr[k] + (size_t)ic * 64, base + k * 2048);
    };
    auto prefA = [&](uint4(&a)[8], int tap, int ic) {
        const u16* base = wtp + (size_t)(tap * nIC + ic) * (64 * M);
#pragma unroll
        for (int pl = 0; pl < 2; ++pl)
#pragma unroll
            for (int mt = 0; mt < 4; ++mt)
                a[pl * 4 + mt] = *(const uint4*)(base + ((size_t)(pl * 4 + lkg) * M + obase + mt * 16) * 8);
    };
    auto ctap = [&](const uint4(&a)[8], int tap, int buf) {
        const u16* bb0 = Bs + buf * BUF_U16;
#pragma unroll
        for (int nf = 0; nf < NF; ++nf) {
            const int tt = nf * 16 + l15;
            const int rw = (S == 2) ? (tt + (tap >> 1)) : (tt + tap);
            const int ph = (S == 2) ? (tap & 1) : 0;
            const int sl = (lkg + (rw >> 1)) & 3;
            const u16* p = bb0 + (size_t)(((vh * 2 * NPH + ph) * R + rw) * 4 + sl) * 8;
            short8v bh = *(const short8v*)p;
            short8v bl = *(const short8v*)(p + PL_STRIDE);
#pragma unroll
            for (int mt = 0; mt < 4; ++mt) {
                short8v ah = __builtin_bit_cast(short8v, a[mt]);
                short8v al = __builtin_bit_cast(short8v, a[4 + mt]);
                acc[mt][nf] = MFMA16(ah, bh, acc[mt][nf], 0, 0, 0);
                acc[mt][nf] = MFMA16(ah, bl, acc[mt][nf], 0, 0, 0);
                acc[mt][nf] = MFMA16(al, bh, acc[mt][nf], 0, 0, 0);
            }
        }
    };

    if (TAPS == 9) {
        stage(0, 0);
        prefA(ar[0], 0, 0);
        prefA(ar[1], 1, 0);
        __syncthreads();
        int cur = 0;
#pragma unroll 1
        for (int ic = 0; ic < nIC; ++ic) {
            if (ic + 1 < nIC) stage(cur ^ 1, ic + 1);
            const int icn = (ic + 1 < nIC) ? ic + 1 : ic;
#pragma unroll
            for (int t = 0; t < 9; ++t) {
                const int tn = (t + 2 < 9) ? (t + 2) : (t - 7);
                const int ici = (t + 2 < 9) ? ic : icn;
                prefA(ar[(t + 2) % 3], tn, ici);
                ctap(ar[t % 3], t, cur);
            }
            __syncthreads();   // drains DMA for next buffer; frees cur buffer
            cur ^= 1;
        }
    } else {
        stage(0, 0);
        prefA(ar[0], 0, 0);
        __syncthreads();
        int cur = 0;
#pragma unroll 1
        for (int ic = 0; ic < nIC; ++ic) {
            if (ic + 1 < nIC) { stage(cur ^ 1, ic + 1); prefA(ar[1], 0, ic + 1); }
            ctap(ar[0], 0, cur);
            __syncthreads();
            cur ^= 1;
            if (ic + 1 < nIC) {
#pragma unroll
                for (int j = 0; j < 8; ++j) ar[0][j] = ar[1][j];
            }
        }
    }

    // ---- epilogue: per 16-o group, LDS transpose (E overlays B), relu, store ----
    u16* dhi = dstb ? dstb + (size_t)nl * dst_nstride : nullptr;
    u16* dlo = dhi ? dhi + dst_poff : nullptr;
    float* outn = OUTF32 ? outb + (size_t)nl * 480000 : nullptr;
#pragma unroll
    for (int m = 0; m < 4; ++m) {
        __syncthreads();
#pragma unroll
        for (int nf = 0; nf < NF; ++nf)
#pragma unroll
            for (int r = 0; r < 4; ++r)
                E[(vh * NT + nf * 16 + l15) * EP + ((VW == 2) ? oh * 16 : 0) + lkg * 4 + r] = acc[m][nf][r];
        __syncthreads();
        if (!OUTF32) {
            constexpr int C16 = (VW == 2) ? 2 : 1;
            for (int q = tid; q < VW * NT * C16; q += 256) {
                int row = q / C16, c16 = q - row * C16;
                int vv = vg * VW + row / NT;
                int tl = row % NT, tg = t0 + tl;
                if (vv < 25 && tg < Tout) {
                    u16 hb[16], lb[16];
#pragma unroll
                    for (int j = 0; j < 16; ++j) {
                        float y = fmaxf(E[row * EP + c16 * 16 + j], 0.f);
                        u16 h = f2bf(y); hb[j] = h; lb[j] = f2bf(y - bf2f(h));
                    }
                    int ob = ot * (VW == 2 ? 128 : 64) + c16 * 64 + m * 16;
                    size_t o = (size_t)(vv * Tout + tg) * M + ob;
                    *(uint4*)&dhi[o] = *(const uint4*)&hb[0];
                    *(uint4*)&dhi[o + 8] = *(const uint4*)&hb[8];
                    *(uint4*)&dlo[o] = *(const uint4*)&lb[0];
                    *(uint4*)&dlo[o + 8] = *(const uint4*)&lb[8];
                }
            }
        } else {
            for (int q = tid; q < 32 * NT; q += 256) {
                int ol = q / NT, tl = q - ol * NT, tg = t0 + tl;
                if (tg < Tout) {
                    int o = ot * 128 + (ol >> 4) * 64 + m * 16 + (ol & 15);
                    float* op = outn + (size_t)o * 1875 + tg * 25 + vg * 2;
#pragma unroll
                    for (int v2 = 0; v2 < 2; ++v2)
                        if (vg * 2 + v2 < 25)
                            op[v2] = fmaxf(E[(v2 * NT + tl) * EP + ol], 0.f);
                }
            }
        }
    }
}

// ===================== host =====================
extern "C" void kernel_launch(void* const* d_in, const int* in_sizes, int n_in,
                              void* d_out, int out_size, void* d_ws, size_t ws_size,
                              hipStream_t stream)
{
    const float* x = (const float*)d_in[0];
    const float* A = (const float*)d_in[1];
    const float* WS[10];
    const float* WT[10];
    for (int i = 0; i < 10; ++i) {
        WS[i] = (const float*)d_in[2 + 2 * i];
        WT[i] = (const float*)d_in[3 + 2 * i];
    }
    float* outF = (float*)d_out;

    static const int KM[10]  = {32, 64, 64, 64, 64, 128, 128, 128, 256, 256};
    static const int MM[10]  = {64, 64, 64, 64, 128, 128, 128, 256, 256, 256};
    static const int TIN[10] = {300, 300, 300, 300, 300, 150, 150, 150, 75, 75};
    static const int SS[10]  = {1, 1, 1, 1, 2, 1, 1, 2, 1, 1};

    // d_ws: [zero page 1024B][prep weights][spill activation zone]
    const u16* zpage = (const u16*)d_ws;
    zinit<<<1, 256, 0, stream>>>((u32*)d_ws);

    size_t mixoff[10], wtoff[10], off = 0;
    for (int b = 0; b < 10; ++b) {
        mixoff[b] = off; off += (size_t)(KM[b] / 32) * 64 * MM[b];
        wtoff[b] = off;  off += (size_t)9 * (MM[b] / 32) * 64 * MM[b];
    }
    u16* prep = (u16*)((char*)d_ws + 1024);
    size_t prep_bytes = ((off * 2 + 255) / 256) * 256;
    u16* ws_s = (u16*)((char*)d_ws + 1024 + prep_bytes);
    size_t ws_spill = (ws_size > prep_bytes + 1024) ? ws_size - prep_bytes - 1024 : 0;

    for (int b = 0; b < 10; ++b) {
        int nICm = KM[b] / 32;
        int totm = nICm * 64 * MM[b];
        prep_w<<<(totm + 255) / 256, 256, 0, stream>>>(
            WS[b], prep + mixoff[b], MM[b], (b == 0 ? 3 : KM[b]), nICm, 1, totm);
        int nICt = MM[b] / 32;
        int tott = 9 * nICt * 64 * MM[b];
        prep_w<<<(tott + 255) / 256, 256, 0, stream>>>(
            WT[b], prep + wtoff[b], MM[b], MM[b], nICt, 9, tott);
    }

    const long F_STR = 960000;
    const long S_STR = 1920000;
    const size_t F_PN_B = 1920000;
    const size_t S_PN_B = 3840000;
    const size_t dout_b = (size_t)out_size * 4;

    int done = 0;
    while (done < 64) {
        size_t used = (size_t)done * F_PN_B;
        size_t dout_rem = dout_b - used;
        int NC = (int)((dout_rem + ws_spill) / (F_PN_B + S_PN_B));
        if (NC > 64 - done) NC = 64 - done;
        if (NC < 1) NC = 1;
        int k_s = 0;
        for (;; --NC) {
            long rem_after_F = (long)dout_rem - (long)NC * (long)F_PN_B;
            k_s = rem_after_F > 0 ? (int)(rem_after_F / (long)S_PN_B) : 0;
            if (k_s > NC) k_s = NC;
            if ((size_t)(NC - k_s) * S_PN_B <= ws_spill) break;
            if (NC <= 1) { NC = 1; k_s = 0; break; }
        }
        u16* Fz = (u16*)d_out + used / 2;
        u16* Sd = (u16*)d_out + (used + (size_t)NC * F_PN_B) / 2;

        for (int b = 0; b < 10; ++b) {
            const int K = KM[b], M = MM[b], Tin = TIN[b], S = SS[b];
            const int Tout = (S == 1) ? Tin : Tin / 2;
            const int fpoff = (b == 0) ? 240000 : 480000;
            const int spoff = 25 * Tin * M;

            if (b == 0)
                adj0<<<dim3(2, NC), 256, 0, stream>>>(
                    x + (size_t)done * 22500, A, Fz, F_STR, 240000);
            else {
                int thr = Tin * (K >> 2);
                adj_ip<<<dim3((thr + 255) / 256, NC), 256, 0, stream>>>(
                    Fz, A, K, Tin, F_STR, 480000);
            }

            for (int part = 0; part < 2; ++part) {
                int n0 = part ? k_s : 0;
                int cnt = part ? NC - k_s : k_s;
                if (cnt <= 0) continue;
                u16* sb = part ? ws_s : Sd;
                u16* fb = Fz + (size_t)n0 * F_STR;

                // ---- mix (TAPS=1): fb -> sb ----
                if (b <= 3) {
                    const int otm = 1, strips = 5;   // VW4, NT64, T=300
                    conv4<4, 64, 1, 1, 0><<<otm * 7 * strips * cnt, 256, 0, stream>>>(
                        fb, prep + mixoff[b], sb, nullptr, K, M, Tin, Tin,
                        F_STR, fpoff, S_STR, spoff, otm, strips, cnt, zpage);
                } else {
                    const int otm = M / 128, strips = (Tin + 79) / 80;  // VW2, NT80
                    conv4<2, 80, 1, 1, 0><<<otm * 13 * strips * cnt, 256, 0, stream>>>(
                        fb, prep + mixoff[b], sb, nullptr, K, M, Tin, Tin,
                        F_STR, fpoff, S_STR, spoff, otm, strips, cnt, zpage);
                }

                // ---- temporal (TAPS=9): sb -> fb (or out for b9) ----
                if (b <= 3) {
                    const int ott = 1, strips = (Tin + 47) / 48;        // VW4, NT48
                    conv4<4, 48, 9, 1, 0><<<ott * 7 * strips * cnt, 256, 0, stream>>>(
                        sb, prep + wtoff[b], fb, nullptr, M, M, Tin, Tout,
                        S_STR, spoff, F_STR, 480000, ott, strips, cnt, zpage);
                } else if (S == 2) {
                    const int ott = M / 128, strips = (Tout + 47) / 48; // VW2, NT48
                    conv4<2, 48, 9, 2, 0><<<ott * 13 * strips * cnt, 256, 0, stream>>>(
                        sb, prep + wtoff[b], fb, nullptr, M, M, Tin, Tout,
                        S_STR, spoff, F_STR, 480000, ott, strips, cnt, zpage);
                } else if (b == 9) {
                    const int ott = 2, strips = 1;                      // VW2, NT80, f32 out
                    conv4<2, 80, 9, 1, 1><<<ott * 13 * strips * cnt, 256, 0, stream>>>(
                        sb, prep + wtoff[b], nullptr,
                        outF + (size_t)(done + n0) * 480000,
                        M, M, Tin, Tout, S_STR, spoff, 0, 0, ott, strips, cnt, zpage);
                } else {
                    const int ott = M / 128, strips = (Tout + 79) / 80; // VW2, NT80
                    conv4<2, 80, 9, 1, 0><<<ott * 13 * strips * cnt, 256, 0, stream>>>(
                        sb, prep + wtoff[b], fb, nullptr, M, M, Tin, Tout,
                        S_STR, spoff, F_STR, 480000, ott, strips, cnt, zpage);
                }
            }
        }
        done += NC;
    }
}